// Round 1
// baseline (3625.375 us; speedup 1.0000x reference)
//
#include <hip/hip_runtime.h>
#include <cstdint>
#include <cstddef>

// ---- threefry mode: 1 = jax_threefry_partitionable (modern default), 0 = original split-halves
#define TF_PARTITIONABLE 1

// ---------------- problem constants ----------------
constexpr int B_ = 8, N_ = 4096, CIN_ = 64, COUT_ = 128;
constexpr int S_ = 1024, NS_ = 32, V_ = 4;
constexpr int ROWS_ = B_ * S_ * NS_;          // 262144

// ---------------- workspace layout (bytes) ----------------
constexpr size_t OFF_ACC   = 0;               // 4376 doubles
constexpr size_t ACC_BYTES = 35072;           // memset region
constexpr size_t OFF_SCALE = 35072;           // 8 f32
constexpr size_t OFF_W1P   = 35328;           // 64*13 f32
constexpr size_t OFF_B1P   = 38656;           // 64 f32
constexpr size_t OFF_WCOMB = 38912;           // 128*64 f32
constexpr size_t OFF_BCOMB = 71680;           // 128 f32
constexpr size_t OFF_MIXWT = 72192;           // 134*64 f32
constexpr size_t OFF_NIDX  = 106496;          // 8192 i32
constexpr size_t OFF_GIDX  = 139264;          // 262144 i32
constexpr size_t OFF_GF    = 1187840;         // 64 MB
constexpr size_t OFF_AGG   = 68296704;        // 64 MB   (total ~129.2 MB)

// acc (double) indices
constexpr int AC_BATCH = 0;    // 8*{sum,sumsq}
constexpr int AC_G     = 16;   // per b: G1[3], G2[6]
constexpr int AC_E     = 88;   // per (b,v): E1, Ea[3]
constexpr int AC_S2A   = 216;  // 64 col sums of agg
constexpr int AC_M2    = 280;  // 64*64 agg'agg

// ---------------- helpers ----------------
__device__ __forceinline__ float gelu_f(float x) {
    return 0.5f * x * (1.0f + erff(x * 0.7071067811865476f));
}

#define TF_ROUND(r) { x0 += x1; x1 = (x1 << (r)) | (x1 >> (32 - (r))); x1 ^= x0; }

__device__ __forceinline__ unsigned tf_random_bits(unsigned lo) {
    const unsigned ks0 = 0u, ks1 = 42u, ks2 = 0x1BD11BDAu ^ 0u ^ 42u;
#if TF_PARTITIONABLE
    unsigned x0 = 0u + ks0, x1 = lo + ks1;        // counter = (hi=0, lo=flat index)
#else
    unsigned j = lo & 0x01FFFFFFu;
    unsigned x0 = j + ks0, x1 = (j + 0x02000000u) + ks1;
#endif
    TF_ROUND(13) TF_ROUND(15) TF_ROUND(26) TF_ROUND(6)
    x0 += ks1; x1 += ks2 + 1u;
    TF_ROUND(17) TF_ROUND(29) TF_ROUND(16) TF_ROUND(24)
    x0 += ks2; x1 += ks0 + 2u;
    TF_ROUND(13) TF_ROUND(15) TF_ROUND(26) TF_ROUND(6)
    x0 += ks0; x1 += ks1 + 3u;
    TF_ROUND(17) TF_ROUND(29) TF_ROUND(16) TF_ROUND(24)
    x0 += ks1; x1 += ks2 + 4u;
    TF_ROUND(13) TF_ROUND(15) TF_ROUND(26) TF_ROUND(6)
    x0 += ks2; x1 += ks0 + 5u;
#if TF_PARTITIONABLE
    return x0 ^ x1;
#else
    return (lo < 0x02000000u) ? x0 : x1;
#endif
}

__device__ __forceinline__ float gumbel_from_bits(unsigned bits) {
    float fl = __uint_as_float((bits >> 9) | 0x3f800000u) - 1.0f;   // [0,1)
    float u  = fmaxf(1e-9f, fl + 1e-9f);                            // jax uniform(1e-9, 1.0)
    return -logf(-logf(u));
}

__device__ __forceinline__ float wsum(float v) {
    for (int o = 32; o; o >>= 1) v += __shfl_down(v, o);
    return v;
}

// ---------------- K1: farthest point sampling ----------------
__global__ __launch_bounds__(1024) void k_fps(const float* __restrict__ xyz,
                                              int* __restrict__ new_idx,
                                              float* __restrict__ new_xyz) {
    __shared__ float sx[4096], sy[4096], sz[4096];
    __shared__ float swv[16];
    __shared__ int   swi[16];
    __shared__ int   s_win;
    int b = blockIdx.x, t = threadIdx.x, lane = t & 63, wid = t >> 6;
    const float* xb = xyz + (size_t)b * 12288;
    for (int i = t; i < 4096; i += 1024) {
        sx[i] = xb[i * 3]; sy[i] = xb[i * 3 + 1]; sz[i] = xb[i * 3 + 2];
    }
    __syncthreads();
    float px[4], py[4], pz[4], md[4];
#pragma unroll
    for (int j = 0; j < 4; j++) {
        int i = t * 4 + j;
        px[j] = sx[i]; py[j] = sy[i]; pz[j] = sz[i];
        md[j] = __builtin_inff();
    }
    if (t == 0) {
        new_idx[b * 1024] = 0;
        new_xyz[(size_t)b * 3072 + 0] = sx[0];
        new_xyz[(size_t)b * 3072 + 1] = sy[0];
        new_xyz[(size_t)b * 3072 + 2] = sz[0];
    }
    int cur = 0;
    for (int it = 1; it < 1024; ++it) {
        float cx = sx[cur], cy = sy[cur], cz = sz[cur];
        float bv = -1.0f; int bi = 0;
#pragma unroll
        for (int j = 0; j < 4; j++) {
            float dx = __fsub_rn(px[j], cx), dy = __fsub_rn(py[j], cy), dz = __fsub_rn(pz[j], cz);
            float d = __fadd_rn(__fadd_rn(__fmul_rn(dx, dx), __fmul_rn(dy, dy)), __fmul_rn(dz, dz));
            float m2 = fminf(md[j], d); md[j] = m2;
            if (m2 > bv) { bv = m2; bi = t * 4 + j; }
        }
        for (int off = 32; off; off >>= 1) {
            float ov = __shfl_down(bv, off);
            int   oi = __shfl_down(bi, off);
            if (ov > bv || (ov == bv && oi < bi)) { bv = ov; bi = oi; }
        }
        if (lane == 0) { swv[wid] = bv; swi[wid] = bi; }
        __syncthreads();
        if (t == 0) {
            float v = swv[0]; int ii = swi[0];
#pragma unroll
            for (int w = 1; w < 16; w++) {
                float ov = swv[w]; int oi = swi[w];
                if (ov > v || (ov == v && oi < ii)) { v = ov; ii = oi; }
            }
            s_win = ii;
            new_idx[b * 1024 + it] = ii;
            size_t o3 = ((size_t)b * 1024 + it) * 3;
            new_xyz[o3] = sx[ii]; new_xyz[o3 + 1] = sy[ii]; new_xyz[o3 + 2] = sz[ii];
        }
        __syncthreads();
        cur = s_win;
    }
}

// ---------------- K2: ball query (first 32 by index within radius) ----------------
__global__ __launch_bounds__(256) void k_ball(const float* __restrict__ xyz,
                                              const float* __restrict__ new_xyz,
                                              int* __restrict__ gidx) {
    int gw = blockIdx.x * 4 + (threadIdx.x >> 6);
    int lane = threadIdx.x & 63;
    int b = gw >> 10;
    const float* xb = xyz + (size_t)b * 12288;
    float qx = new_xyz[gw * 3], qy = new_xyz[gw * 3 + 1], qz = new_xyz[gw * 3 + 2];
    int* out = gidx + (size_t)gw * 32;
    int have = 0;
    for (int c0 = 0; c0 < 4096; c0 += 64) {
        int i = c0 + lane;
        float dx = __fsub_rn(qx, xb[i * 3]);
        float dy = __fsub_rn(qy, xb[i * 3 + 1]);
        float dz = __fsub_rn(qz, xb[i * 3 + 2]);
        float d2 = __fadd_rn(__fadd_rn(__fmul_rn(dx, dx), __fmul_rn(dy, dy)), __fmul_rn(dz, dz));
        bool within = d2 < 0.04f;
        unsigned long long mv = __ballot(within);
        int rank = __popcll(mv & ((1ull << lane) - 1ull));
        int pos = have + rank;
        if (within && pos < 32) out[pos] = i;
        have += (int)__popcll(mv);
        if (have >= 32) break;
    }
    for (int j = have + lane; j < 32; j += 64) out[j] = -1;
}

// ---------------- K3: gather pass -> gf std moments + rel group moments ----------------
__global__ __launch_bounds__(256) void k_stats(const float* __restrict__ xyz,
                                               const float* __restrict__ f,
                                               const int* __restrict__ cidx,
                                               const int* __restrict__ new_idx,
                                               const int* __restrict__ gidx,
                                               const float* __restrict__ new_xyz,
                                               double* __restrict__ acc) {
    int b = blockIdx.x >> 5, blk = blockIdx.x & 31;
    int t = threadIdx.x, lane = t & 63;
    const float* xb = xyz + (size_t)b * 12288;
    const float* fb = f + ((size_t)b << 18);
    float mc[4][3];
#pragma unroll
    for (int v = 0; v < 4; v++) {
        int ci = cidx[v];
        mc[v][0] = xb[ci * 3]; mc[v][1] = xb[ci * 3 + 1]; mc[v][2] = xb[ci * 3 + 2];
    }
    float sum = 0.f, ssq = 0.f;
    float G1x = 0, G1y = 0, G1z = 0, Gxx = 0, Gxy = 0, Gxz = 0, Gyy = 0, Gyz = 0, Gzz = 0;
    float E1[4] = {0, 0, 0, 0}, Eax[4] = {0, 0, 0, 0}, Eay[4] = {0, 0, 0, 0}, Eaz[4] = {0, 0, 0, 0};
    for (int rr = 0; rr < 4; ++rr) {
        int row = blk * 1024 + rr * 256 + t;
        int s = row >> 5;
        int gi = gidx[((size_t)b << 15) + row];
        bool msk = gi < 0;
        int sg = (b << 10) + s;
        float nx = new_xyz[sg * 3], ny = new_xyz[sg * 3 + 1], nz = new_xyz[sg * 3 + 2];
        int nid = new_idx[sg];
        float gx = 0, gy = 0, gz = 0;
        if (!msk) { gx = xb[gi * 3]; gy = xb[gi * 3 + 1]; gz = xb[gi * 3 + 2]; }
        float a3 = __fsub_rn(gx, nx), a4 = __fsub_rn(gy, ny), a5 = __fsub_rn(gz, nz);
        sum += gx + gy + gz + a3 + a4 + a5;
        ssq += gx * gx + gy * gy + gz * gz + a3 * a3 + a4 * a4 + a5 * a5;
        const float4* fsp = (const float4*)(fb + ((size_t)nid << 6));
        int gi0 = msk ? 0 : gi;
        const float4* fip = (const float4*)(fb + ((size_t)gi0 << 6));
#pragma unroll
        for (int c4 = 0; c4 < 16; c4++) {
            float4 fs4 = fsp[c4];
            float4 fi4 = fip[c4];
            if (msk) { fi4.x = 0; fi4.y = 0; fi4.z = 0; fi4.w = 0; }
            float d0 = __fsub_rn(fi4.x, fs4.x), d1 = __fsub_rn(fi4.y, fs4.y);
            float d2 = __fsub_rn(fi4.z, fs4.z), d3 = __fsub_rn(fi4.w, fs4.w);
            sum += d0 + d1 + d2 + d3;
            ssq += d0 * d0 + d1 * d1 + d2 * d2 + d3 * d3;
        }
        G1x += gx; G1y += gy; G1z += gz;
        Gxx += gx * gx; Gxy += gx * gy; Gxz += gx * gz;
        Gyy += gy * gy; Gyz += gy * gz; Gzz += gz * gz;
#pragma unroll
        for (int v = 0; v < 4; v++) {
            float ax = __fsub_rn(gx, mc[v][0]), ay = __fsub_rn(gy, mc[v][1]), az = __fsub_rn(gz, mc[v][2]);
            float e = __fsqrt_rn(ax * ax + ay * ay + az * az);
            E1[v] += e; Eax[v] += e * gx; Eay[v] += e * gy; Eaz[v] += e * gz;
        }
    }
    sum = wsum(sum); ssq = wsum(ssq);
    G1x = wsum(G1x); G1y = wsum(G1y); G1z = wsum(G1z);
    Gxx = wsum(Gxx); Gxy = wsum(Gxy); Gxz = wsum(Gxz);
    Gyy = wsum(Gyy); Gyz = wsum(Gyz); Gzz = wsum(Gzz);
#pragma unroll
    for (int v = 0; v < 4; v++) {
        E1[v] = wsum(E1[v]); Eax[v] = wsum(Eax[v]); Eay[v] = wsum(Eay[v]); Eaz[v] = wsum(Eaz[v]);
    }
    if (lane == 0) {
        atomicAdd(&acc[AC_BATCH + b * 2 + 0], (double)sum);
        atomicAdd(&acc[AC_BATCH + b * 2 + 1], (double)ssq);
        double* Gb = acc + AC_G + b * 9;
        atomicAdd(&Gb[0], (double)G1x); atomicAdd(&Gb[1], (double)G1y); atomicAdd(&Gb[2], (double)G1z);
        atomicAdd(&Gb[3], (double)Gxx); atomicAdd(&Gb[4], (double)Gxy); atomicAdd(&Gb[5], (double)Gxz);
        atomicAdd(&Gb[6], (double)Gyy); atomicAdd(&Gb[7], (double)Gyz); atomicAdd(&Gb[8], (double)Gzz);
#pragma unroll
        for (int v = 0; v < 4; v++) {
            double* Eb = acc + AC_E + (b * 4 + v) * 4;
            atomicAdd(&Eb[0], (double)E1[v]);
            atomicAdd(&Eb[1], (double)Eax[v]);
            atomicAdd(&Eb[2], (double)Eay[v]);
            atomicAdd(&Eb[3], (double)Eaz[v]);
        }
    }
}

// ---------------- K4: prep (std scale, BN1 fold, mix_w transpose) ----------------
struct GS { double G1[3]; double G2[6]; double E1; double Ea[3]; double m[3]; };

__device__ __forceinline__ int g2i(int x, int y) {
    if (x > y) { int tt = x; x = y; y = tt; }
    return (x == 0) ? y : ((x == 1) ? (2 + y) : 5);
}

__device__ double pairsum(const GS& g, int ki, int ai, int kj, int aj) {
    const double R = 32768.0;
    if (ki > kj) { int tk = ki; ki = kj; kj = tk; int ta = ai; ai = aj; aj = ta; }
    switch (ki * 4 + kj) {
        case 0:  return g.G2[g2i(ai, aj)] - g.m[ai] * g.G1[aj] - g.m[aj] * g.G1[ai] + R * g.m[ai] * g.m[aj];
        case 1:  return g.Ea[ai] - g.m[ai] * g.E1;
        case 2:  return g.G2[g2i(ai, aj)] - g.m[ai] * g.G1[aj];
        case 3:  return (g.G1[ai] - R * g.m[ai]) * g.m[aj];
        case 5:  { double s = 0; for (int x = 0; x < 3; x++) s += g.G2[g2i(x, x)] - 2.0 * g.m[x] * g.G1[x] + R * g.m[x] * g.m[x]; return s; }
        case 6:  return g.Ea[aj];
        case 7:  return g.E1 * g.m[aj];
        case 10: return g.G2[g2i(ai, aj)];
        case 11: return g.G1[ai] * g.m[aj];
        case 15: return R * g.m[ai] * g.m[aj];
    }
    return 0.0;
}

__device__ __forceinline__ void chdec(int ch, int& kind, int& ax, double& sgn) {
    if (ch < 3)      { kind = 0; ax = ch;      sgn = -1.0; }
    else if (ch < 6) { kind = 0; ax = ch - 3;  sgn = 1.0; }
    else if (ch == 6){ kind = 1; ax = 0;       sgn = 1.0; }
    else if (ch < 10){ kind = 2; ax = ch - 7;  sgn = 1.0; }
    else             { kind = 3; ax = ch - 10; sgn = 1.0; }
}

__device__ GS load_gs(const double* acc, const float* xyz, const int* cidx, int grp) {
    GS g; int b = grp >> 2, v = grp & 3;
    const double* Gb = acc + AC_G + b * 9;
    g.G1[0] = Gb[0]; g.G1[1] = Gb[1]; g.G1[2] = Gb[2];
    for (int q = 0; q < 6; q++) g.G2[q] = Gb[3 + q];
    const double* Eb = acc + AC_E + grp * 4;
    g.E1 = Eb[0]; g.Ea[0] = Eb[1]; g.Ea[1] = Eb[2]; g.Ea[2] = Eb[3];
    int ci = cidx[v];
    g.m[0] = (double)xyz[(size_t)b * 12288 + ci * 3];
    g.m[1] = (double)xyz[(size_t)b * 12288 + ci * 3 + 1];
    g.m[2] = (double)xyz[(size_t)b * 12288 + ci * 3 + 2];
    return g;
}

__global__ __launch_bounds__(256) void k_prep(const double* __restrict__ acc,
                                              const float* __restrict__ xyz,
                                              const int* __restrict__ cidx,
                                              const float* __restrict__ m1w1,
                                              const float* __restrict__ m1b1,
                                              const float* __restrict__ m1g1,
                                              const float* __restrict__ m1be1,
                                              const float* __restrict__ mixw,
                                              float* __restrict__ scale,
                                              float* __restrict__ w1p,
                                              float* __restrict__ b1p,
                                              float* __restrict__ mixwt) {
    __shared__ double Sec[169];
    __shared__ double S1[13];
    int t = threadIdx.x;
    if (t < 8) {
        double sm = acc[AC_BATCH + t * 2], sq = acc[AC_BATCH + t * 2 + 1];
        double M = 2293760.0;
        double var = (sq - sm * sm / M) / (M - 1.0);
        float stdv = (float)sqrt(var);
        scale[t] = 1.0f / (stdv + 1e-5f);
    }
    for (int idx = t; idx < 8576; idx += 256) {
        int k = idx >> 6, o = idx & 63;
        mixwt[idx] = mixw[o * 134 + k];
    }
    if (t < 169) {
        int i = t / 13, j = t % 13;
        int ki, ai, kj, aj; double si, sj;
        chdec(i, ki, ai, si); chdec(j, kj, aj, sj);
        double val = 0;
        for (int grp = 0; grp < 32; grp++) {
            GS g = load_gs(acc, xyz, cidx, grp);
            val += si * sj * pairsum(g, ki, ai, kj, aj);
        }
        Sec[t] = val;
    } else if (t < 182) {
        int i = t - 169;
        int ki, ai; double si;
        chdec(i, ki, ai, si);
        double val = 0;
        const double R = 32768.0;
        for (int grp = 0; grp < 32; grp++) {
            GS g = load_gs(acc, xyz, cidx, grp);
            double tv;
            switch (ki) {
                case 0:  tv = si * (g.G1[ai] - R * g.m[ai]); break;
                case 1:  tv = g.E1; break;
                case 2:  tv = g.G1[ai]; break;
                default: tv = R * g.m[ai]; break;
            }
            val += tv;
        }
        S1[i] = val;
    }
    __syncthreads();
    if (t < 64) {
        double w[13];
        for (int k = 0; k < 13; k++) w[k] = (double)m1w1[t * 13 + k];
        double s1w = 0;
        for (int k = 0; k < 13; k++) s1w += w[k] * S1[k];
        double quad = 0;
        for (int i = 0; i < 13; i++) {
            double s = 0;
            for (int j = 0; j < 13; j++) s += Sec[i * 13 + j] * w[j];
            quad += w[i] * s;
        }
        double M1d = 1048576.0;
        double b1o = (double)m1b1[t];
        double mu = s1w / M1d + b1o;
        double E2 = (quad + 2.0 * b1o * s1w) / M1d + b1o * b1o;
        double var = E2 - mu * mu;
        double gg = (double)m1g1[t] / sqrt(var + 1e-5);
        for (int k = 0; k < 13; k++) w1p[t * 13 + k] = (float)(w[k] * gg);
        b1p[t] = (float)((b1o - mu) * gg + (double)m1be1[t]);
    }
}

// ---------------- K5: grouped_f = affine(gf)/std .. concat sampled -> mix GEMM ----------------
__global__ __launch_bounds__(256) void k_groupedf(const float* __restrict__ xyz,
                                                  const float* __restrict__ f,
                                                  const int* __restrict__ new_idx,
                                                  const int* __restrict__ gidx,
                                                  const float* __restrict__ new_xyz,
                                                  const float* __restrict__ scale_p,
                                                  const float* __restrict__ aw,
                                                  const float* __restrict__ ab,
                                                  const float* __restrict__ mixwt,
                                                  const float* __restrict__ mixb,
                                                  float* __restrict__ gf) {
    int r = blockIdx.x * 256 + threadIdx.x;
    int b = r >> 15;
    int rb = r & 32767;
    int s = rb >> 5;
    int gi = gidx[r];
    bool msk = gi < 0;
    int gi0 = msk ? 0 : gi;
    int sg = (b << 10) + s;
    int nid = new_idx[sg];
    float scale = scale_p[b];
    float nx = new_xyz[sg * 3], ny = new_xyz[sg * 3 + 1], nz = new_xyz[sg * 3 + 2];
    const float* xb = xyz + (size_t)b * 12288;
    const float* fb = f + ((size_t)b << 18);
    float gx = 0, gy = 0, gz = 0;
    if (!msk) { gx = xb[gi * 3]; gy = xb[gi * 3 + 1]; gz = xb[gi * 3 + 2]; }
    float acc[64];
#pragma unroll
    for (int o = 0; o < 64; o++) acc[o] = mixb[o];
    float va[6];
    va[0] = gx; va[1] = gy; va[2] = gz;
    va[3] = __fsub_rn(gx, nx); va[4] = __fsub_rn(gy, ny); va[5] = __fsub_rn(gz, nz);
#pragma unroll
    for (int k = 0; k < 6; k++) {
        float g = aw[k] * (va[k] * scale) + ab[k];
        const float* wt = mixwt + k * 64;
#pragma unroll
        for (int o = 0; o < 64; o++) acc[o] += g * wt[o];
    }
    const float4* fip = (const float4*)(fb + ((size_t)gi0 << 6));
    const float4* fsp = (const float4*)(fb + ((size_t)nid << 6));
    for (int c4 = 0; c4 < 16; c4++) {
        float4 fi = fip[c4];
        if (msk) { fi.x = 0; fi.y = 0; fi.z = 0; fi.w = 0; }
        float4 fs4 = fsp[c4];
        float dv[4] = {__fsub_rn(fi.x, fs4.x), __fsub_rn(fi.y, fs4.y),
                       __fsub_rn(fi.z, fs4.z), __fsub_rn(fi.w, fs4.w)};
#pragma unroll
        for (int u = 0; u < 4; u++) {
            int k = 6 + c4 * 4 + u;
            float g = aw[k] * (dv[u] * scale) + ab[k];
            const float* wt = mixwt + k * 64;
#pragma unroll
            for (int o = 0; o < 64; o++) acc[o] += g * wt[o];
        }
    }
    for (int c4 = 0; c4 < 16; c4++) {
        float4 fs4 = fsp[c4];
        float sv[4] = {fs4.x, fs4.y, fs4.z, fs4.w};
#pragma unroll
        for (int u = 0; u < 4; u++) {
            int k = 70 + c4 * 4 + u;
            const float* wt = mixwt + k * 64;
#pragma unroll
            for (int o = 0; o < 64; o++) acc[o] += sv[u] * wt[o];
        }
    }
    float4* dst = (float4*)(gf + ((size_t)r << 6));
#pragma unroll
    for (int c4 = 0; c4 < 16; c4++)
        dst[c4] = make_float4(acc[c4 * 4], acc[c4 * 4 + 1], acc[c4 * 4 + 2], acc[c4 * 4 + 3]);
}

// ---------------- K6: fused m1 -> gelu -> m1_w2 -> logits -> gumbel softmax -> agg ----------------
__global__ __launch_bounds__(256) void k_fused(const float* __restrict__ xyz,
                                               const int* __restrict__ cidx,
                                               const int* __restrict__ gidx,
                                               const float* __restrict__ gf,
                                               const float* __restrict__ w1p,
                                               const float* __restrict__ b1p,
                                               const float* __restrict__ w2,
                                               const float* __restrict__ b2,
                                               float* __restrict__ agg) {
    __shared__ float sh[4][4][64];
    __shared__ float smc[4][3];
    int t = threadIdx.x, wv = t >> 6, lane = t & 63;
    int row0 = blockIdx.x * 64;
    int b = row0 >> 15;
    if (t < 12) {
        int v = t / 3, j = t % 3;
        smc[v][j] = xyz[(size_t)b * 12288 + cidx[v] * 3 + j];
    }
    float w1l[13];
#pragma unroll
    for (int k = 0; k < 13; k++) w1l[k] = w1p[lane * 13 + k];
    float b1l = b1p[lane], b2l = b2[lane];
    float w2r[64];
#pragma unroll
    for (int c4 = 0; c4 < 16; c4++) {
        float4 tmp = *(const float4*)(w2 + lane * 64 + c4 * 4);
        w2r[c4 * 4] = tmp.x; w2r[c4 * 4 + 1] = tmp.y; w2r[c4 * 4 + 2] = tmp.z; w2r[c4 * 4 + 3] = tmp.w;
    }
    __syncthreads();
    float mcl[4][3];
#pragma unroll
    for (int v = 0; v < 4; v++) { mcl[v][0] = smc[v][0]; mcl[v][1] = smc[v][1]; mcl[v][2] = smc[v][2]; }
    int r = row0 + wv * 16;
    for (int rr = 0; rr < 16; ++rr, ++r) {
        int gi = gidx[r];
        bool msk = gi < 0;
        float gx = 0, gy = 0, gz = 0;
        if (!msk) {
            const float* p = xyz + (size_t)b * 12288 + (size_t)gi * 3;
            gx = p[0]; gy = p[1]; gz = p[2];
        }
        float gfo = gf[((size_t)r << 6) + lane];
#pragma unroll
        for (int v = 0; v < 4; v++) {
            float ax = __fsub_rn(gx, mcl[v][0]);
            float ay = __fsub_rn(gy, mcl[v][1]);
            float az = __fsub_rn(gz, mcl[v][2]);
            float eu = __fsqrt_rn(__fadd_rn(__fadd_rn(__fmul_rn(ax, ax), __fmul_rn(ay, ay)), __fmul_rn(az, az)));
            float h = b1l
                - ax * w1l[0] - ay * w1l[1] - az * w1l[2]
                + ax * w1l[3] + ay * w1l[4] + az * w1l[5]
                + eu * w1l[6] + gx * w1l[7] + gy * w1l[8] + gz * w1l[9]
                + mcl[v][0] * w1l[10] + mcl[v][1] * w1l[11] + mcl[v][2] * w1l[12];
            sh[wv][v][lane] = gelu_f(h);
        }
        __syncthreads();
        float lg[4];
#pragma unroll
        for (int v = 0; v < 4; v++) {
            float a = b2l;
            const float4* hp = (const float4*)sh[wv][v];
#pragma unroll
            for (int c4 = 0; c4 < 16; c4++) {
                float4 hh = hp[c4];
                a += hh.x * w2r[c4 * 4] + hh.y * w2r[c4 * 4 + 1] + hh.z * w2r[c4 * 4 + 2] + hh.w * w2r[c4 * 4 + 3];
            }
            lg[v] = gfo * a;
        }
        __syncthreads();
        unsigned base = ((unsigned)r << 8) + (unsigned)lane;
        float z0 = lg[0] + gumbel_from_bits(tf_random_bits(base));
        float z1 = lg[1] + gumbel_from_bits(tf_random_bits(base + 64u));
        float z2 = lg[2] + gumbel_from_bits(tf_random_bits(base + 128u));
        float z3 = lg[3] + gumbel_from_bits(tf_random_bits(base + 192u));
        float mx = fmaxf(fmaxf(z0, z1), fmaxf(z2, z3));
        float e0 = __expf(z0 - mx), e1 = __expf(z1 - mx), e2 = __expf(z2 - mx), e3 = __expf(z3 - mx);
        float inv = 1.0f / (e0 + e1 + e2 + e3);
        float av = (e0 * lg[0] + e1 * lg[1] + e2 * lg[2] + e3 * lg[3]) * inv + gfo;
        agg[((size_t)r << 6) + lane] = msk ? 0.0f : av;
    }
}

// ---------------- K7: syrk — M2 = agg' * agg, col sums ----------------
__global__ __launch_bounds__(256) void k_syrk(const float* __restrict__ agg,
                                              double* __restrict__ acc) {
    __shared__ float As[128][64];
    int t = threadIdx.x;
    int ti = t >> 4, tj = t & 15;
    float C[4][4] = {};
    float cs = 0.f;
    size_t base = (size_t)blockIdx.x * 1024 * 64;
    for (int tile = 0; tile < 8; ++tile) {
        const float4* src = (const float4*)(agg + base + (size_t)tile * 128 * 64);
#pragma unroll
        for (int i = 0; i < 8; i++) {
            int idx = t + i * 256;
            ((float4*)As)[idx] = src[idx];
        }
        __syncthreads();
        for (int rr = 0; rr < 128; ++rr) {
            float4 a = *(const float4*)&As[rr][ti * 4];
            float4 bb = *(const float4*)&As[rr][tj * 4];
            C[0][0] += a.x * bb.x; C[0][1] += a.x * bb.y; C[0][2] += a.x * bb.z; C[0][3] += a.x * bb.w;
            C[1][0] += a.y * bb.x; C[1][1] += a.y * bb.y; C[1][2] += a.y * bb.z; C[1][3] += a.y * bb.w;
            C[2][0] += a.z * bb.x; C[2][1] += a.z * bb.y; C[2][2] += a.z * bb.z; C[2][3] += a.z * bb.w;
            C[3][0] += a.w * bb.x; C[3][1] += a.w * bb.y; C[3][2] += a.w * bb.z; C[3][3] += a.w * bb.w;
            if (t < 64) cs += As[rr][t];
        }
        __syncthreads();
    }
    double* M2 = acc + AC_M2;
#pragma unroll
    for (int i = 0; i < 4; i++)
#pragma unroll
        for (int j = 0; j < 4; j++)
            atomicAdd(&M2[(ti * 4 + i) * 64 + (tj * 4 + j)], (double)C[i][j]);
    if (t < 64) atomicAdd(&acc[AC_S2A + t], (double)cs);
}

// ---------------- K7b: BN2 stats -> fold into W_comb / b_comb ----------------
__global__ __launch_bounds__(256) void k_comb(const double* __restrict__ acc,
                                              const float* __restrict__ m2w1,
                                              const float* __restrict__ m2b1,
                                              const float* __restrict__ m2g1,
                                              const float* __restrict__ m2be1,
                                              const float* __restrict__ m2w2,
                                              const float* __restrict__ m2b2,
                                              float* __restrict__ wcomb,
                                              float* __restrict__ bcomb) {
    __shared__ float W1s[128 * 64];
    __shared__ float g2s[128], ofss[128];
    int t = threadIdx.x;
    const double* S2a = acc + AC_S2A;
    const double* M2 = acc + AC_M2;
    if (t < 128) {
        float wf[64];
        for (int c = 0; c < 64; c++) wf[c] = m2w1[t * 64 + c];
        double sw = 0;
        for (int c = 0; c < 64; c++) sw += (double)wf[c] * S2a[c];
        double quad = 0;
        for (int i = 0; i < 64; i++) {
            double s = 0;
            for (int j = 0; j < 64; j++) s += (double)wf[j] * M2[i * 64 + j];
            quad += (double)wf[i] * s;
        }
        double Rd = 262144.0;
        double b1o = (double)m2b1[t];
        double mu = sw / Rd + b1o;
        double E2 = (quad + 2.0 * b1o * sw) / Rd + b1o * b1o;
        double var = E2 - mu * mu;
        double gg = (double)m2g1[t] / sqrt(var + 1e-5);
        g2s[t] = (float)gg;
        ofss[t] = (float)(((double)m2b1[t] - mu) * gg + (double)m2be1[t]);
    }
    __syncthreads();
    for (int idx = t; idx < 128 * 64; idx += 256) {
        int c = idx >> 6, k = idx & 63;
        W1s[idx] = g2s[c] * m2w1[c * 64 + k];
    }
    __syncthreads();
    for (int idx = t; idx < 128 * 64; idx += 256) {
        int o = idx >> 6, k = idx & 63;
        float s = 0;
        for (int c = 0; c < 128; c++) s += m2w2[o * 128 + c] * W1s[c * 64 + k];
        wcomb[idx] = s;
    }
    if (t < 128) {
        float s = m2b2[t];
        for (int c = 0; c < 128; c++) s += m2w2[t * 128 + c] * ofss[c];
        bcomb[t] = s;
    }
}

// ---------------- K8: final — composed m2 + res, gelu, max over NS ----------------
__global__ __launch_bounds__(256) void k_final(const float* __restrict__ agg,
                                               const float* __restrict__ gf,
                                               const float* __restrict__ wcomb,
                                               const float* __restrict__ bcomb,
                                               const float* __restrict__ resw,
                                               const float* __restrict__ resb,
                                               float* __restrict__ out_f) {
    __shared__ float rbuf[8][128];
    int t = threadIdx.x, wv = t >> 6, lane = t & 63;
    int which = lane >> 5, n = lane & 31;
    int gw = blockIdx.x * 8 + wv * 2 + which;
    size_t r = (size_t)gw * 32 + n;
    float ar[64], sk[64];
    const float4* ap = (const float4*)(agg + (r << 6));
    const float4* sp = (const float4*)(gf + (r << 6));
#pragma unroll
    for (int c4 = 0; c4 < 16; c4++) {
        float4 x = ap[c4];
        ar[c4 * 4] = x.x; ar[c4 * 4 + 1] = x.y; ar[c4 * 4 + 2] = x.z; ar[c4 * 4 + 3] = x.w;
        float4 y = sp[c4];
        sk[c4 * 4] = y.x; sk[c4 * 4 + 1] = y.y; sk[c4 * 4 + 2] = y.z; sk[c4 * 4 + 3] = y.w;
    }
    for (int o = 0; o < 128; o++) {
        float a1 = bcomb[o], a2 = resb[o];
        const float* wc = wcomb + o * 64;
        const float* rw = resw + o * 64;
#pragma unroll
        for (int c = 0; c < 64; c++) { a1 += ar[c] * wc[c]; a2 += sk[c] * rw[c]; }
        float g = gelu_f(a1 + a2);
#pragma unroll
        for (int off = 16; off; off >>= 1) g = fmaxf(g, __shfl_xor(g, off));
        if (n == 0) rbuf[wv * 2 + which][o] = g;
    }
    __syncthreads();
    int base = blockIdx.x * 8;
    for (int i = t; i < 1024; i += 256) {
        int lr = i >> 7, o = i & 127;
        out_f[(size_t)(base + lr) * 128 + o] = rbuf[lr][o];
    }
}

// ---------------- launch ----------------
extern "C" void kernel_launch(void* const* d_in, const int* in_sizes, int n_in,
                              void* d_out, int out_size, void* d_ws, size_t ws_size,
                              hipStream_t stream) {
    (void)in_sizes; (void)n_in; (void)out_size; (void)ws_size;
    const float* xyz  = (const float*)d_in[0];
    const float* f    = (const float*)d_in[1];
    const int*   cidx = (const int*)d_in[2];
    const float* aw   = (const float*)d_in[3];
    const float* ab   = (const float*)d_in[4];
    const float* mixw = (const float*)d_in[5];
    const float* mixb = (const float*)d_in[6];
    const float* m1w1 = (const float*)d_in[7];
    const float* m1b1 = (const float*)d_in[8];
    const float* m1g1 = (const float*)d_in[9];
    const float* m1be1= (const float*)d_in[10];
    const float* m1w2 = (const float*)d_in[11];
    const float* m1b2 = (const float*)d_in[12];
    const float* m2w1 = (const float*)d_in[13];
    const float* m2b1 = (const float*)d_in[14];
    const float* m2g1 = (const float*)d_in[15];
    const float* m2be1= (const float*)d_in[16];
    const float* m2w2 = (const float*)d_in[17];
    const float* m2b2 = (const float*)d_in[18];
    const float* resw = (const float*)d_in[19];
    const float* resb = (const float*)d_in[20];

    float* out_f   = (float*)d_out;
    float* out_xyz = out_f + (size_t)B_ * S_ * COUT_;

    char* ws = (char*)d_ws;
    double* acc  = (double*)(ws + OFF_ACC);
    float* scale = (float*)(ws + OFF_SCALE);
    float* w1p   = (float*)(ws + OFF_W1P);
    float* b1p   = (float*)(ws + OFF_B1P);
    float* wcomb = (float*)(ws + OFF_WCOMB);
    float* bcomb = (float*)(ws + OFF_BCOMB);
    float* mixwt = (float*)(ws + OFF_MIXWT);
    int*   nidx  = (int*)(ws + OFF_NIDX);
    int*   gidx  = (int*)(ws + OFF_GIDX);
    float* gf    = (float*)(ws + OFF_GF);
    float* agg   = (float*)(ws + OFF_AGG);

    hipMemsetAsync(ws, 0, ACC_BYTES, stream);
    hipLaunchKernelGGL(k_fps,      dim3(8),    dim3(1024), 0, stream, xyz, nidx, out_xyz);
    hipLaunchKernelGGL(k_ball,     dim3(2048), dim3(256),  0, stream, xyz, out_xyz, gidx);
    hipLaunchKernelGGL(k_stats,    dim3(256),  dim3(256),  0, stream, xyz, f, cidx, nidx, gidx, out_xyz, acc);
    hipLaunchKernelGGL(k_prep,     dim3(1),    dim3(256),  0, stream, acc, xyz, cidx, m1w1, m1b1, m1g1, m1be1, mixw, scale, w1p, b1p, mixwt);
    hipLaunchKernelGGL(k_groupedf, dim3(1024), dim3(256),  0, stream, xyz, f, nidx, gidx, out_xyz, scale, aw, ab, mixwt, mixb, gf);
    hipLaunchKernelGGL(k_fused,    dim3(4096), dim3(256),  0, stream, xyz, cidx, gidx, gf, w1p, b1p, m1w2, m1b2, agg);
    hipLaunchKernelGGL(k_syrk,     dim3(256),  dim3(256),  0, stream, agg, acc);
    hipLaunchKernelGGL(k_comb,     dim3(1),    dim3(256),  0, stream, acc, m2w1, m2b1, m2g1, m2be1, m2w2, m2b2, wcomb, bcomb);
    hipLaunchKernelGGL(k_final,    dim3(1024), dim3(256),  0, stream, agg, gf, wcomb, bcomb, resw, resb, out_f);
}

// Round 2
// 2236.470 us; speedup vs baseline: 1.6210x; 1.6210x over previous
//
#include <hip/hip_runtime.h>
#include <cstdint>
#include <cstddef>

// ---- threefry mode: 1 = jax_threefry_partitionable (modern default), 0 = original split-halves
#define TF_PARTITIONABLE 1

// ---------------- problem constants ----------------
constexpr int B_ = 8, N_ = 4096, CIN_ = 64, COUT_ = 128;
constexpr int S_ = 1024, NS_ = 32, V_ = 4;
constexpr int ROWS_ = B_ * S_ * NS_;          // 262144

// ---------------- workspace layout (bytes) ----------------
constexpr size_t OFF_ACC   = 0;               // 4376 doubles
constexpr size_t ACC_BYTES = 35072;           // memset region
constexpr size_t OFF_SCALE = 35072;           // 8 f32
constexpr size_t OFF_W1P   = 35328;           // 64*13 f32
constexpr size_t OFF_B1P   = 38656;           // 64 f32
constexpr size_t OFF_WCOMB = 38912;           // 128*64 f32
constexpr size_t OFF_BCOMB = 71680;           // 128 f32
constexpr size_t OFF_MIXWT = 72192;           // 134*64 f32
constexpr size_t OFF_NIDX  = 106496;          // 8192 i32
constexpr size_t OFF_GIDX  = 139264;          // 262144 i32
constexpr size_t OFF_GF    = 1187840;         // 64 MB
constexpr size_t OFF_AGG   = 68296704;        // 64 MB   (total ~129.2 MB)

// acc (double) indices
constexpr int AC_BATCH = 0;    // 8*{sum,sumsq}
constexpr int AC_G     = 16;   // per b: G1[3], G2[6]
constexpr int AC_E     = 88;   // per (b,v): E1, Ea[3]
constexpr int AC_S2A   = 216;  // 64 col sums of agg
constexpr int AC_M2    = 280;  // 64*64 agg'agg

// ---------------- helpers ----------------
__device__ __forceinline__ float gelu_f(float x) {
    return 0.5f * x * (1.0f + erff(x * 0.7071067811865476f));
}

#define TF_ROUND(r) { x0 += x1; x1 = (x1 << (r)) | (x1 >> (32 - (r))); x1 ^= x0; }

__device__ __forceinline__ unsigned tf_random_bits(unsigned lo) {
    const unsigned ks0 = 0u, ks1 = 42u, ks2 = 0x1BD11BDAu ^ 0u ^ 42u;
#if TF_PARTITIONABLE
    unsigned x0 = 0u + ks0, x1 = lo + ks1;        // counter = (hi=0, lo=flat index)
#else
    unsigned j = lo & 0x01FFFFFFu;
    unsigned x0 = j + ks0, x1 = (j + 0x02000000u) + ks1;
#endif
    TF_ROUND(13) TF_ROUND(15) TF_ROUND(26) TF_ROUND(6)
    x0 += ks1; x1 += ks2 + 1u;
    TF_ROUND(17) TF_ROUND(29) TF_ROUND(16) TF_ROUND(24)
    x0 += ks2; x1 += ks0 + 2u;
    TF_ROUND(13) TF_ROUND(15) TF_ROUND(26) TF_ROUND(6)
    x0 += ks0; x1 += ks1 + 3u;
    TF_ROUND(17) TF_ROUND(29) TF_ROUND(16) TF_ROUND(24)
    x0 += ks1; x1 += ks2 + 4u;
    TF_ROUND(13) TF_ROUND(15) TF_ROUND(26) TF_ROUND(6)
    x0 += ks2; x1 += ks0 + 5u;
#if TF_PARTITIONABLE
    return x0 ^ x1;
#else
    return (lo < 0x02000000u) ? x0 : x1;
#endif
}

__device__ __forceinline__ float gumbel_from_bits(unsigned bits) {
    float fl = __uint_as_float((bits >> 9) | 0x3f800000u) - 1.0f;   // [0,1)
    float u  = fmaxf(1e-9f, fl + 1e-9f);                            // jax uniform(1e-9, 1.0)
    return -logf(-logf(u));
}

__device__ __forceinline__ float wsum(float v) {
    for (int o = 32; o; o >>= 1) v += __shfl_down(v, o);
    return v;
}

// ---------------- K1: farthest point sampling (latency-optimized) ----------------
// 256 threads / 4 waves, 16 points per thread in VGPRs. Per iteration:
//   value-only xor-butterfly wave max -> ballot to find winner lane (lowest lane
//   = lowest point index, preserving jnp.argmax first-max tie-break) -> leaders
//   write (val,idx) to parity-double-buffered LDS -> ONE barrier -> every thread
//   selects the block winner itself (no re-broadcast barrier) and reads winner
//   coords from an LDS mirror of the cloud.
__global__ __launch_bounds__(256) void k_fps(const float* __restrict__ xyz,
                                             int* __restrict__ new_idx,
                                             float* __restrict__ new_xyz) {
    __shared__ float sx[4096], sy[4096], sz[4096];
    __shared__ __align__(16) float swv[2][4];
    __shared__ __align__(16) int   swi[2][4];
    int b = blockIdx.x, t = threadIdx.x, lane = t & 63, wid = t >> 6;
    const float* xb = xyz + (size_t)b * 12288;
    float px[16], py[16], pz[16], md[16];
    int i0 = t * 16;
#pragma unroll
    for (int j = 0; j < 16; j++) {
        int i = i0 + j;
        float x = xb[i * 3], y = xb[i * 3 + 1], z = xb[i * 3 + 2];
        px[j] = x; py[j] = y; pz[j] = z;
        sx[i] = x; sy[i] = y; sz[i] = z;
        md[j] = __builtin_inff();
    }
    __syncthreads();
    float cx = sx[0], cy = sy[0], cz = sz[0];
    if (t == 0) {
        new_idx[b * 1024] = 0;
        new_xyz[(size_t)b * 3072 + 0] = cx;
        new_xyz[(size_t)b * 3072 + 1] = cy;
        new_xyz[(size_t)b * 3072 + 2] = cz;
    }
    int p = 0;
    for (int it = 1; it < 1024; ++it) {
        float bv = -1.0f; int bj = 0;
#pragma unroll
        for (int j = 0; j < 16; j++) {
            float dx = __fsub_rn(px[j], cx), dy = __fsub_rn(py[j], cy), dz = __fsub_rn(pz[j], cz);
            float d = __fadd_rn(__fadd_rn(__fmul_rn(dx, dx), __fmul_rn(dy, dy)), __fmul_rn(dz, dz));
            float m2 = fminf(md[j], d); md[j] = m2;
            if (m2 > bv) { bv = m2; bj = j; }
        }
        int bi = i0 + bj;
        // value-only butterfly: all lanes get the wave max
        float mx = bv;
#pragma unroll
        for (int off = 1; off < 64; off <<= 1) mx = fmaxf(mx, __shfl_xor(mx, off));
        unsigned long long msk = __ballot(bv == mx);
        int winlane = __ffsll(msk) - 1;
        int wbi = __shfl(bi, winlane);
        if (lane == 0) { swv[p][wid] = mx; swi[p][wid] = wbi; }
        __syncthreads();
        float4 vv = *(const float4*)&swv[p][0];
        int4   ii4 = *(const int4*)&swi[p][0];
        float best = vv.x; int ii = ii4.x;
        if (vv.y > best) { best = vv.y; ii = ii4.y; }
        if (vv.z > best) { best = vv.z; ii = ii4.z; }
        if (vv.w > best) { best = vv.w; ii = ii4.w; }
        cx = sx[ii]; cy = sy[ii]; cz = sz[ii];
        if (t == 0) {
            new_idx[b * 1024 + it] = ii;
            size_t o3 = ((size_t)b * 1024 + it) * 3;
            new_xyz[o3] = cx; new_xyz[o3 + 1] = cy; new_xyz[o3 + 2] = cz;
        }
        p ^= 1;
    }
}

// ---------------- K2: ball query (first 32 by index within radius) ----------------
__global__ __launch_bounds__(256) void k_ball(const float* __restrict__ xyz,
                                              const float* __restrict__ new_xyz,
                                              int* __restrict__ gidx) {
    int gw = blockIdx.x * 4 + (threadIdx.x >> 6);
    int lane = threadIdx.x & 63;
    int b = gw >> 10;
    const float* xb = xyz + (size_t)b * 12288;
    float qx = new_xyz[gw * 3], qy = new_xyz[gw * 3 + 1], qz = new_xyz[gw * 3 + 2];
    int* out = gidx + (size_t)gw * 32;
    int have = 0;
    for (int c0 = 0; c0 < 4096; c0 += 64) {
        int i = c0 + lane;
        float dx = __fsub_rn(qx, xb[i * 3]);
        float dy = __fsub_rn(qy, xb[i * 3 + 1]);
        float dz = __fsub_rn(qz, xb[i * 3 + 2]);
        float d2 = __fadd_rn(__fadd_rn(__fmul_rn(dx, dx), __fmul_rn(dy, dy)), __fmul_rn(dz, dz));
        bool within = d2 < 0.04f;
        unsigned long long mv = __ballot(within);
        int rank = __popcll(mv & ((1ull << lane) - 1ull));
        int pos = have + rank;
        if (within && pos < 32) out[pos] = i;
        have += (int)__popcll(mv);
        if (have >= 32) break;
    }
    for (int j = have + lane; j < 32; j += 64) out[j] = -1;
}

// ---------------- K3: gather pass -> gf std moments + rel group moments ----------------
__global__ __launch_bounds__(256) void k_stats(const float* __restrict__ xyz,
                                               const float* __restrict__ f,
                                               const int* __restrict__ cidx,
                                               const int* __restrict__ new_idx,
                                               const int* __restrict__ gidx,
                                               const float* __restrict__ new_xyz,
                                               double* __restrict__ acc) {
    int b = blockIdx.x >> 5, blk = blockIdx.x & 31;
    int t = threadIdx.x, lane = t & 63;
    const float* xb = xyz + (size_t)b * 12288;
    const float* fb = f + ((size_t)b << 18);
    float mc[4][3];
#pragma unroll
    for (int v = 0; v < 4; v++) {
        int ci = cidx[v];
        mc[v][0] = xb[ci * 3]; mc[v][1] = xb[ci * 3 + 1]; mc[v][2] = xb[ci * 3 + 2];
    }
    float sum = 0.f, ssq = 0.f;
    float G1x = 0, G1y = 0, G1z = 0, Gxx = 0, Gxy = 0, Gxz = 0, Gyy = 0, Gyz = 0, Gzz = 0;
    float E1[4] = {0, 0, 0, 0}, Eax[4] = {0, 0, 0, 0}, Eay[4] = {0, 0, 0, 0}, Eaz[4] = {0, 0, 0, 0};
    for (int rr = 0; rr < 4; ++rr) {
        int row = blk * 1024 + rr * 256 + t;
        int s = row >> 5;
        int gi = gidx[((size_t)b << 15) + row];
        bool msk = gi < 0;
        int sg = (b << 10) + s;
        float nx = new_xyz[sg * 3], ny = new_xyz[sg * 3 + 1], nz = new_xyz[sg * 3 + 2];
        int nid = new_idx[sg];
        float gx = 0, gy = 0, gz = 0;
        if (!msk) { gx = xb[gi * 3]; gy = xb[gi * 3 + 1]; gz = xb[gi * 3 + 2]; }
        float a3 = __fsub_rn(gx, nx), a4 = __fsub_rn(gy, ny), a5 = __fsub_rn(gz, nz);
        sum += gx + gy + gz + a3 + a4 + a5;
        ssq += gx * gx + gy * gy + gz * gz + a3 * a3 + a4 * a4 + a5 * a5;
        const float4* fsp = (const float4*)(fb + ((size_t)nid << 6));
        int gi0 = msk ? 0 : gi;
        const float4* fip = (const float4*)(fb + ((size_t)gi0 << 6));
#pragma unroll
        for (int c4 = 0; c4 < 16; c4++) {
            float4 fs4 = fsp[c4];
            float4 fi4 = fip[c4];
            if (msk) { fi4.x = 0; fi4.y = 0; fi4.z = 0; fi4.w = 0; }
            float d0 = __fsub_rn(fi4.x, fs4.x), d1 = __fsub_rn(fi4.y, fs4.y);
            float d2 = __fsub_rn(fi4.z, fs4.z), d3 = __fsub_rn(fi4.w, fs4.w);
            sum += d0 + d1 + d2 + d3;
            ssq += d0 * d0 + d1 * d1 + d2 * d2 + d3 * d3;
        }
        G1x += gx; G1y += gy; G1z += gz;
        Gxx += gx * gx; Gxy += gx * gy; Gxz += gx * gz;
        Gyy += gy * gy; Gyz += gy * gz; Gzz += gz * gz;
#pragma unroll
        for (int v = 0; v < 4; v++) {
            float ax = __fsub_rn(gx, mc[v][0]), ay = __fsub_rn(gy, mc[v][1]), az = __fsub_rn(gz, mc[v][2]);
            float e = __fsqrt_rn(ax * ax + ay * ay + az * az);
            E1[v] += e; Eax[v] += e * gx; Eay[v] += e * gy; Eaz[v] += e * gz;
        }
    }
    sum = wsum(sum); ssq = wsum(ssq);
    G1x = wsum(G1x); G1y = wsum(G1y); G1z = wsum(G1z);
    Gxx = wsum(Gxx); Gxy = wsum(Gxy); Gxz = wsum(Gxz);
    Gyy = wsum(Gyy); Gyz = wsum(Gyz); Gzz = wsum(Gzz);
#pragma unroll
    for (int v = 0; v < 4; v++) {
        E1[v] = wsum(E1[v]); Eax[v] = wsum(Eax[v]); Eay[v] = wsum(Eay[v]); Eaz[v] = wsum(Eaz[v]);
    }
    if (lane == 0) {
        atomicAdd(&acc[AC_BATCH + b * 2 + 0], (double)sum);
        atomicAdd(&acc[AC_BATCH + b * 2 + 1], (double)ssq);
        double* Gb = acc + AC_G + b * 9;
        atomicAdd(&Gb[0], (double)G1x); atomicAdd(&Gb[1], (double)G1y); atomicAdd(&Gb[2], (double)G1z);
        atomicAdd(&Gb[3], (double)Gxx); atomicAdd(&Gb[4], (double)Gxy); atomicAdd(&Gb[5], (double)Gxz);
        atomicAdd(&Gb[6], (double)Gyy); atomicAdd(&Gb[7], (double)Gyz); atomicAdd(&Gb[8], (double)Gzz);
#pragma unroll
        for (int v = 0; v < 4; v++) {
            double* Eb = acc + AC_E + (b * 4 + v) * 4;
            atomicAdd(&Eb[0], (double)E1[v]);
            atomicAdd(&Eb[1], (double)Eax[v]);
            atomicAdd(&Eb[2], (double)Eay[v]);
            atomicAdd(&Eb[3], (double)Eaz[v]);
        }
    }
}

// ---------------- K4: prep (std scale, BN1 fold, mix_w transpose) ----------------
struct GS { double G1[3]; double G2[6]; double E1; double Ea[3]; double m[3]; };

__device__ __forceinline__ int g2i(int x, int y) {
    if (x > y) { int tt = x; x = y; y = tt; }
    return (x == 0) ? y : ((x == 1) ? (2 + y) : 5);
}

__device__ double pairsum(const GS& g, int ki, int ai, int kj, int aj) {
    const double R = 32768.0;
    if (ki > kj) { int tk = ki; ki = kj; kj = tk; int ta = ai; ai = aj; aj = ta; }
    switch (ki * 4 + kj) {
        case 0:  return g.G2[g2i(ai, aj)] - g.m[ai] * g.G1[aj] - g.m[aj] * g.G1[ai] + R * g.m[ai] * g.m[aj];
        case 1:  return g.Ea[ai] - g.m[ai] * g.E1;
        case 2:  return g.G2[g2i(ai, aj)] - g.m[ai] * g.G1[aj];
        case 3:  return (g.G1[ai] - R * g.m[ai]) * g.m[aj];
        case 5:  { double s = 0; for (int x = 0; x < 3; x++) s += g.G2[g2i(x, x)] - 2.0 * g.m[x] * g.G1[x] + R * g.m[x] * g.m[x]; return s; }
        case 6:  return g.Ea[aj];
        case 7:  return g.E1 * g.m[aj];
        case 10: return g.G2[g2i(ai, aj)];
        case 11: return g.G1[ai] * g.m[aj];
        case 15: return R * g.m[ai] * g.m[aj];
    }
    return 0.0;
}

__device__ __forceinline__ void chdec(int ch, int& kind, int& ax, double& sgn) {
    if (ch < 3)      { kind = 0; ax = ch;      sgn = -1.0; }
    else if (ch < 6) { kind = 0; ax = ch - 3;  sgn = 1.0; }
    else if (ch == 6){ kind = 1; ax = 0;       sgn = 1.0; }
    else if (ch < 10){ kind = 2; ax = ch - 7;  sgn = 1.0; }
    else             { kind = 3; ax = ch - 10; sgn = 1.0; }
}

__device__ GS load_gs(const double* acc, const float* xyz, const int* cidx, int grp) {
    GS g; int b = grp >> 2, v = grp & 3;
    const double* Gb = acc + AC_G + b * 9;
    g.G1[0] = Gb[0]; g.G1[1] = Gb[1]; g.G1[2] = Gb[2];
    for (int q = 0; q < 6; q++) g.G2[q] = Gb[3 + q];
    const double* Eb = acc + AC_E + grp * 4;
    g.E1 = Eb[0]; g.Ea[0] = Eb[1]; g.Ea[1] = Eb[2]; g.Ea[2] = Eb[3];
    int ci = cidx[v];
    g.m[0] = (double)xyz[(size_t)b * 12288 + ci * 3];
    g.m[1] = (double)xyz[(size_t)b * 12288 + ci * 3 + 1];
    g.m[2] = (double)xyz[(size_t)b * 12288 + ci * 3 + 2];
    return g;
}

__global__ __launch_bounds__(256) void k_prep(const double* __restrict__ acc,
                                              const float* __restrict__ xyz,
                                              const int* __restrict__ cidx,
                                              const float* __restrict__ m1w1,
                                              const float* __restrict__ m1b1,
                                              const float* __restrict__ m1g1,
                                              const float* __restrict__ m1be1,
                                              const float* __restrict__ mixw,
                                              float* __restrict__ scale,
                                              float* __restrict__ w1p,
                                              float* __restrict__ b1p,
                                              float* __restrict__ mixwt) {
    __shared__ double Sec[169];
    __shared__ double S1[13];
    int t = threadIdx.x;
    if (t < 8) {
        double sm = acc[AC_BATCH + t * 2], sq = acc[AC_BATCH + t * 2 + 1];
        double M = 2293760.0;
        double var = (sq - sm * sm / M) / (M - 1.0);
        float stdv = (float)sqrt(var);
        scale[t] = 1.0f / (stdv + 1e-5f);
    }
    for (int idx = t; idx < 8576; idx += 256) {
        int k = idx >> 6, o = idx & 63;
        mixwt[idx] = mixw[o * 134 + k];
    }
    if (t < 169) {
        int i = t / 13, j = t % 13;
        int ki, ai, kj, aj; double si, sj;
        chdec(i, ki, ai, si); chdec(j, kj, aj, sj);
        double val = 0;
        for (int grp = 0; grp < 32; grp++) {
            GS g = load_gs(acc, xyz, cidx, grp);
            val += si * sj * pairsum(g, ki, ai, kj, aj);
        }
        Sec[t] = val;
    } else if (t < 182) {
        int i = t - 169;
        int ki, ai; double si;
        chdec(i, ki, ai, si);
        double val = 0;
        const double R = 32768.0;
        for (int grp = 0; grp < 32; grp++) {
            GS g = load_gs(acc, xyz, cidx, grp);
            double tv;
            switch (ki) {
                case 0:  tv = si * (g.G1[ai] - R * g.m[ai]); break;
                case 1:  tv = g.E1; break;
                case 2:  tv = g.G1[ai]; break;
                default: tv = R * g.m[ai]; break;
            }
            val += tv;
        }
        S1[i] = val;
    }
    __syncthreads();
    if (t < 64) {
        double w[13];
        for (int k = 0; k < 13; k++) w[k] = (double)m1w1[t * 13 + k];
        double s1w = 0;
        for (int k = 0; k < 13; k++) s1w += w[k] * S1[k];
        double quad = 0;
        for (int i = 0; i < 13; i++) {
            double s = 0;
            for (int j = 0; j < 13; j++) s += Sec[i * 13 + j] * w[j];
            quad += w[i] * s;
        }
        double M1d = 1048576.0;
        double b1o = (double)m1b1[t];
        double mu = s1w / M1d + b1o;
        double E2 = (quad + 2.0 * b1o * s1w) / M1d + b1o * b1o;
        double var = E2 - mu * mu;
        double gg = (double)m1g1[t] / sqrt(var + 1e-5);
        for (int k = 0; k < 13; k++) w1p[t * 13 + k] = (float)(w[k] * gg);
        b1p[t] = (float)((b1o - mu) * gg + (double)m1be1[t]);
    }
}

// ---------------- K5: grouped_f = affine(gf)/std .. concat sampled -> mix GEMM ----------------
__global__ __launch_bounds__(256) void k_groupedf(const float* __restrict__ xyz,
                                                  const float* __restrict__ f,
                                                  const int* __restrict__ new_idx,
                                                  const int* __restrict__ gidx,
                                                  const float* __restrict__ new_xyz,
                                                  const float* __restrict__ scale_p,
                                                  const float* __restrict__ aw,
                                                  const float* __restrict__ ab,
                                                  const float* __restrict__ mixwt,
                                                  const float* __restrict__ mixb,
                                                  float* __restrict__ gf) {
    int r = blockIdx.x * 256 + threadIdx.x;
    int b = r >> 15;
    int rb = r & 32767;
    int s = rb >> 5;
    int gi = gidx[r];
    bool msk = gi < 0;
    int gi0 = msk ? 0 : gi;
    int sg = (b << 10) + s;
    int nid = new_idx[sg];
    float scale = scale_p[b];
    float nx = new_xyz[sg * 3], ny = new_xyz[sg * 3 + 1], nz = new_xyz[sg * 3 + 2];
    const float* xb = xyz + (size_t)b * 12288;
    const float* fb = f + ((size_t)b << 18);
    float gx = 0, gy = 0, gz = 0;
    if (!msk) { gx = xb[gi * 3]; gy = xb[gi * 3 + 1]; gz = xb[gi * 3 + 2]; }
    float acc[64];
#pragma unroll
    for (int o = 0; o < 64; o++) acc[o] = mixb[o];
    float va[6];
    va[0] = gx; va[1] = gy; va[2] = gz;
    va[3] = __fsub_rn(gx, nx); va[4] = __fsub_rn(gy, ny); va[5] = __fsub_rn(gz, nz);
#pragma unroll
    for (int k = 0; k < 6; k++) {
        float g = aw[k] * (va[k] * scale) + ab[k];
        const float* wt = mixwt + k * 64;
#pragma unroll
        for (int o = 0; o < 64; o++) acc[o] += g * wt[o];
    }
    const float4* fip = (const float4*)(fb + ((size_t)gi0 << 6));
    const float4* fsp = (const float4*)(fb + ((size_t)nid << 6));
    for (int c4 = 0; c4 < 16; c4++) {
        float4 fi = fip[c4];
        if (msk) { fi.x = 0; fi.y = 0; fi.z = 0; fi.w = 0; }
        float4 fs4 = fsp[c4];
        float dv[4] = {__fsub_rn(fi.x, fs4.x), __fsub_rn(fi.y, fs4.y),
                       __fsub_rn(fi.z, fs4.z), __fsub_rn(fi.w, fs4.w)};
#pragma unroll
        for (int u = 0; u < 4; u++) {
            int k = 6 + c4 * 4 + u;
            float g = aw[k] * (dv[u] * scale) + ab[k];
            const float* wt = mixwt + k * 64;
#pragma unroll
            for (int o = 0; o < 64; o++) acc[o] += g * wt[o];
        }
    }
    for (int c4 = 0; c4 < 16; c4++) {
        float4 fs4 = fsp[c4];
        float sv[4] = {fs4.x, fs4.y, fs4.z, fs4.w};
#pragma unroll
        for (int u = 0; u < 4; u++) {
            int k = 70 + c4 * 4 + u;
            const float* wt = mixwt + k * 64;
#pragma unroll
            for (int o = 0; o < 64; o++) acc[o] += sv[u] * wt[o];
        }
    }
    float4* dst = (float4*)(gf + ((size_t)r << 6));
#pragma unroll
    for (int c4 = 0; c4 < 16; c4++)
        dst[c4] = make_float4(acc[c4 * 4], acc[c4 * 4 + 1], acc[c4 * 4 + 2], acc[c4 * 4 + 3]);
}

// ---------------- K6: fused m1 -> gelu -> m1_w2 -> logits -> gumbel softmax -> agg ----------------
__global__ __launch_bounds__(256) void k_fused(const float* __restrict__ xyz,
                                               const int* __restrict__ cidx,
                                               const int* __restrict__ gidx,
                                               const float* __restrict__ gf,
                                               const float* __restrict__ w1p,
                                               const float* __restrict__ b1p,
                                               const float* __restrict__ w2,
                                               const float* __restrict__ b2,
                                               float* __restrict__ agg) {
    __shared__ float sh[4][4][64];
    __shared__ float smc[4][3];
    int t = threadIdx.x, wv = t >> 6, lane = t & 63;
    int row0 = blockIdx.x * 64;
    int b = row0 >> 15;
    if (t < 12) {
        int v = t / 3, j = t % 3;
        smc[v][j] = xyz[(size_t)b * 12288 + cidx[v] * 3 + j];
    }
    float w1l[13];
#pragma unroll
    for (int k = 0; k < 13; k++) w1l[k] = w1p[lane * 13 + k];
    float b1l = b1p[lane], b2l = b2[lane];
    float w2r[64];
#pragma unroll
    for (int c4 = 0; c4 < 16; c4++) {
        float4 tmp = *(const float4*)(w2 + lane * 64 + c4 * 4);
        w2r[c4 * 4] = tmp.x; w2r[c4 * 4 + 1] = tmp.y; w2r[c4 * 4 + 2] = tmp.z; w2r[c4 * 4 + 3] = tmp.w;
    }
    __syncthreads();
    float mcl[4][3];
#pragma unroll
    for (int v = 0; v < 4; v++) { mcl[v][0] = smc[v][0]; mcl[v][1] = smc[v][1]; mcl[v][2] = smc[v][2]; }
    int r = row0 + wv * 16;
    for (int rr = 0; rr < 16; ++rr, ++r) {
        int gi = gidx[r];
        bool msk = gi < 0;
        float gx = 0, gy = 0, gz = 0;
        if (!msk) {
            const float* p = xyz + (size_t)b * 12288 + (size_t)gi * 3;
            gx = p[0]; gy = p[1]; gz = p[2];
        }
        float gfo = gf[((size_t)r << 6) + lane];
#pragma unroll
        for (int v = 0; v < 4; v++) {
            float ax = __fsub_rn(gx, mcl[v][0]);
            float ay = __fsub_rn(gy, mcl[v][1]);
            float az = __fsub_rn(gz, mcl[v][2]);
            float eu = __fsqrt_rn(__fadd_rn(__fadd_rn(__fmul_rn(ax, ax), __fmul_rn(ay, ay)), __fmul_rn(az, az)));
            float h = b1l
                - ax * w1l[0] - ay * w1l[1] - az * w1l[2]
                + ax * w1l[3] + ay * w1l[4] + az * w1l[5]
                + eu * w1l[6] + gx * w1l[7] + gy * w1l[8] + gz * w1l[9]
                + mcl[v][0] * w1l[10] + mcl[v][1] * w1l[11] + mcl[v][2] * w1l[12];
            sh[wv][v][lane] = gelu_f(h);
        }
        __syncthreads();
        float lg[4];
#pragma unroll
        for (int v = 0; v < 4; v++) {
            float a = b2l;
            const float4* hp = (const float4*)sh[wv][v];
#pragma unroll
            for (int c4 = 0; c4 < 16; c4++) {
                float4 hh = hp[c4];
                a += hh.x * w2r[c4 * 4] + hh.y * w2r[c4 * 4 + 1] + hh.z * w2r[c4 * 4 + 2] + hh.w * w2r[c4 * 4 + 3];
            }
            lg[v] = gfo * a;
        }
        __syncthreads();
        unsigned base = ((unsigned)r << 8) + (unsigned)lane;
        float z0 = lg[0] + gumbel_from_bits(tf_random_bits(base));
        float z1 = lg[1] + gumbel_from_bits(tf_random_bits(base + 64u));
        float z2 = lg[2] + gumbel_from_bits(tf_random_bits(base + 128u));
        float z3 = lg[3] + gumbel_from_bits(tf_random_bits(base + 192u));
        float mx = fmaxf(fmaxf(z0, z1), fmaxf(z2, z3));
        float e0 = __expf(z0 - mx), e1 = __expf(z1 - mx), e2 = __expf(z2 - mx), e3 = __expf(z3 - mx);
        float inv = 1.0f / (e0 + e1 + e2 + e3);
        float av = (e0 * lg[0] + e1 * lg[1] + e2 * lg[2] + e3 * lg[3]) * inv + gfo;
        agg[((size_t)r << 6) + lane] = msk ? 0.0f : av;
    }
}

// ---------------- K7: syrk — M2 = agg' * agg, col sums ----------------
__global__ __launch_bounds__(256) void k_syrk(const float* __restrict__ agg,
                                              double* __restrict__ acc) {
    __shared__ float As[128][64];
    int t = threadIdx.x;
    int ti = t >> 4, tj = t & 15;
    float C[4][4] = {};
    float cs = 0.f;
    size_t base = (size_t)blockIdx.x * 1024 * 64;
    for (int tile = 0; tile < 8; ++tile) {
        const float4* src = (const float4*)(agg + base + (size_t)tile * 128 * 64);
#pragma unroll
        for (int i = 0; i < 8; i++) {
            int idx = t + i * 256;
            ((float4*)As)[idx] = src[idx];
        }
        __syncthreads();
        for (int rr = 0; rr < 128; ++rr) {
            float4 a = *(const float4*)&As[rr][ti * 4];
            float4 bb = *(const float4*)&As[rr][tj * 4];
            C[0][0] += a.x * bb.x; C[0][1] += a.x * bb.y; C[0][2] += a.x * bb.z; C[0][3] += a.x * bb.w;
            C[1][0] += a.y * bb.x; C[1][1] += a.y * bb.y; C[1][2] += a.y * bb.z; C[1][3] += a.y * bb.w;
            C[2][0] += a.z * bb.x; C[2][1] += a.z * bb.y; C[2][2] += a.z * bb.z; C[2][3] += a.z * bb.w;
            C[3][0] += a.w * bb.x; C[3][1] += a.w * bb.y; C[3][2] += a.w * bb.z; C[3][3] += a.w * bb.w;
            if (t < 64) cs += As[rr][t];
        }
        __syncthreads();
    }
    double* M2 = acc + AC_M2;
#pragma unroll
    for (int i = 0; i < 4; i++)
#pragma unroll
        for (int j = 0; j < 4; j++)
            atomicAdd(&M2[(ti * 4 + i) * 64 + (tj * 4 + j)], (double)C[i][j]);
    if (t < 64) atomicAdd(&acc[AC_S2A + t], (double)cs);
}

// ---------------- K7b: BN2 stats -> fold into W_comb / b_comb ----------------
__global__ __launch_bounds__(256) void k_comb(const double* __restrict__ acc,
                                              const float* __restrict__ m2w1,
                                              const float* __restrict__ m2b1,
                                              const float* __restrict__ m2g1,
                                              const float* __restrict__ m2be1,
                                              const float* __restrict__ m2w2,
                                              const float* __restrict__ m2b2,
                                              float* __restrict__ wcomb,
                                              float* __restrict__ bcomb) {
    __shared__ float W1s[128 * 64];
    __shared__ float g2s[128], ofss[128];
    int t = threadIdx.x;
    const double* S2a = acc + AC_S2A;
    const double* M2 = acc + AC_M2;
    if (t < 128) {
        float wf[64];
        for (int c = 0; c < 64; c++) wf[c] = m2w1[t * 64 + c];
        double sw = 0;
        for (int c = 0; c < 64; c++) sw += (double)wf[c] * S2a[c];
        double quad = 0;
        for (int i = 0; i < 64; i++) {
            double s = 0;
            for (int j = 0; j < 64; j++) s += (double)wf[j] * M2[i * 64 + j];
            quad += (double)wf[i] * s;
        }
        double Rd = 262144.0;
        double b1o = (double)m2b1[t];
        double mu = sw / Rd + b1o;
        double E2 = (quad + 2.0 * b1o * sw) / Rd + b1o * b1o;
        double var = E2 - mu * mu;
        double gg = (double)m2g1[t] / sqrt(var + 1e-5);
        g2s[t] = (float)gg;
        ofss[t] = (float)(((double)m2b1[t] - mu) * gg + (double)m2be1[t]);
    }
    __syncthreads();
    for (int idx = t; idx < 128 * 64; idx += 256) {
        int c = idx >> 6, k = idx & 63;
        W1s[idx] = g2s[c] * m2w1[c * 64 + k];
    }
    __syncthreads();
    for (int idx = t; idx < 128 * 64; idx += 256) {
        int o = idx >> 6, k = idx & 63;
        float s = 0;
        for (int c = 0; c < 128; c++) s += m2w2[o * 128 + c] * W1s[c * 64 + k];
        wcomb[idx] = s;
    }
    if (t < 128) {
        float s = m2b2[t];
        for (int c = 0; c < 128; c++) s += m2w2[t * 128 + c] * ofss[c];
        bcomb[t] = s;
    }
}

// ---------------- K8: final — composed m2 + res, gelu, max over NS ----------------
__global__ __launch_bounds__(256) void k_final(const float* __restrict__ agg,
                                               const float* __restrict__ gf,
                                               const float* __restrict__ wcomb,
                                               const float* __restrict__ bcomb,
                                               const float* __restrict__ resw,
                                               const float* __restrict__ resb,
                                               float* __restrict__ out_f) {
    __shared__ float rbuf[8][128];
    int t = threadIdx.x, wv = t >> 6, lane = t & 63;
    int which = lane >> 5, n = lane & 31;
    int gw = blockIdx.x * 8 + wv * 2 + which;
    size_t r = (size_t)gw * 32 + n;
    float ar[64], sk[64];
    const float4* ap = (const float4*)(agg + (r << 6));
    const float4* sp = (const float4*)(gf + (r << 6));
#pragma unroll
    for (int c4 = 0; c4 < 16; c4++) {
        float4 x = ap[c4];
        ar[c4 * 4] = x.x; ar[c4 * 4 + 1] = x.y; ar[c4 * 4 + 2] = x.z; ar[c4 * 4 + 3] = x.w;
        float4 y = sp[c4];
        sk[c4 * 4] = y.x; sk[c4 * 4 + 1] = y.y; sk[c4 * 4 + 2] = y.z; sk[c4 * 4 + 3] = y.w;
    }
    for (int o = 0; o < 128; o++) {
        float a1 = bcomb[o], a2 = resb[o];
        const float* wc = wcomb + o * 64;
        const float* rw = resw + o * 64;
#pragma unroll
        for (int c = 0; c < 64; c++) { a1 += ar[c] * wc[c]; a2 += sk[c] * rw[c]; }
        float g = gelu_f(a1 + a2);
#pragma unroll
        for (int off = 16; off; off >>= 1) g = fmaxf(g, __shfl_xor(g, off));
        if (n == 0) rbuf[wv * 2 + which][o] = g;
    }
    __syncthreads();
    int base = blockIdx.x * 8;
    for (int i = t; i < 1024; i += 256) {
        int lr = i >> 7, o = i & 127;
        out_f[(size_t)(base + lr) * 128 + o] = rbuf[lr][o];
    }
}

// ---------------- launch ----------------
extern "C" void kernel_launch(void* const* d_in, const int* in_sizes, int n_in,
                              void* d_out, int out_size, void* d_ws, size_t ws_size,
                              hipStream_t stream) {
    (void)in_sizes; (void)n_in; (void)out_size; (void)ws_size;
    const float* xyz  = (const float*)d_in[0];
    const float* f    = (const float*)d_in[1];
    const int*   cidx = (const int*)d_in[2];
    const float* aw   = (const float*)d_in[3];
    const float* ab   = (const float*)d_in[4];
    const float* mixw = (const float*)d_in[5];
    const float* mixb = (const float*)d_in[6];
    const float* m1w1 = (const float*)d_in[7];
    const float* m1b1 = (const float*)d_in[8];
    const float* m1g1 = (const float*)d_in[9];
    const float* m1be1= (const float*)d_in[10];
    const float* m1w2 = (const float*)d_in[11];
    const float* m1b2 = (const float*)d_in[12];
    const float* m2w1 = (const float*)d_in[13];
    const float* m2b1 = (const float*)d_in[14];
    const float* m2g1 = (const float*)d_in[15];
    const float* m2be1= (const float*)d_in[16];
    const float* m2w2 = (const float*)d_in[17];
    const float* m2b2 = (const float*)d_in[18];
    const float* resw = (const float*)d_in[19];
    const float* resb = (const float*)d_in[20];

    float* out_f   = (float*)d_out;
    float* out_xyz = out_f + (size_t)B_ * S_ * COUT_;

    char* ws = (char*)d_ws;
    double* acc  = (double*)(ws + OFF_ACC);
    float* scale = (float*)(ws + OFF_SCALE);
    float* w1p   = (float*)(ws + OFF_W1P);
    float* b1p   = (float*)(ws + OFF_B1P);
    float* wcomb = (float*)(ws + OFF_WCOMB);
    float* bcomb = (float*)(ws + OFF_BCOMB);
    float* mixwt = (float*)(ws + OFF_MIXWT);
    int*   nidx  = (int*)(ws + OFF_NIDX);
    int*   gidx  = (int*)(ws + OFF_GIDX);
    float* gf    = (float*)(ws + OFF_GF);
    float* agg   = (float*)(ws + OFF_AGG);

    hipMemsetAsync(ws, 0, ACC_BYTES, stream);
    hipLaunchKernelGGL(k_fps,      dim3(8),    dim3(256),  0, stream, xyz, nidx, out_xyz);
    hipLaunchKernelGGL(k_ball,     dim3(2048), dim3(256),  0, stream, xyz, out_xyz, gidx);
    hipLaunchKernelGGL(k_stats,    dim3(256),  dim3(256),  0, stream, xyz, f, cidx, nidx, gidx, out_xyz, acc);
    hipLaunchKernelGGL(k_prep,     dim3(1),    dim3(256),  0, stream, acc, xyz, cidx, m1w1, m1b1, m1g1, m1be1, mixw, scale, w1p, b1p, mixwt);
    hipLaunchKernelGGL(k_groupedf, dim3(1024), dim3(256),  0, stream, xyz, f, nidx, gidx, out_xyz, scale, aw, ab, mixwt, mixb, gf);
    hipLaunchKernelGGL(k_fused,    dim3(4096), dim3(256),  0, stream, xyz, cidx, gidx, gf, w1p, b1p, m1w2, m1b2, agg);
    hipLaunchKernelGGL(k_syrk,     dim3(256),  dim3(256),  0, stream, agg, acc);
    hipLaunchKernelGGL(k_comb,     dim3(1),    dim3(256),  0, stream, acc, m2w1, m2b1, m2g1, m2be1, m2w2, m2b2, wcomb, bcomb);
    hipLaunchKernelGGL(k_final,    dim3(1024), dim3(256),  0, stream, agg, gf, wcomb, bcomb, resw, resb, out_f);
}

// Round 3
// 2000.066 us; speedup vs baseline: 1.8126x; 1.1182x over previous
//
#include <hip/hip_runtime.h>
#include <cstdint>
#include <cstddef>

// ---- threefry mode: 1 = jax_threefry_partitionable (modern default), 0 = original split-halves
#define TF_PARTITIONABLE 1

// ---------------- problem constants ----------------
constexpr int B_ = 8, N_ = 4096, CIN_ = 64, COUT_ = 128;
constexpr int S_ = 1024, NS_ = 32, V_ = 4;
constexpr int ROWS_ = B_ * S_ * NS_;          // 262144

// ---------------- workspace layout (bytes) ----------------
constexpr size_t OFF_ACC   = 0;               // 4376 doubles
constexpr size_t ACC_BYTES = 35072;           // memset region
constexpr size_t OFF_SCALE = 35072;           // 8 f32
constexpr size_t OFF_W1P   = 35328;           // 64*13 f32
constexpr size_t OFF_B1P   = 38656;           // 64 f32
constexpr size_t OFF_WCOMB = 38912;           // 128*64 f32
constexpr size_t OFF_BCOMB = 71680;           // 128 f32
constexpr size_t OFF_MIXWT = 72192;           // 134*64 f32
constexpr size_t OFF_NIDX  = 106496;          // 8192 i32
constexpr size_t OFF_GIDX  = 139264;          // 262144 i32
constexpr size_t OFF_GF    = 1187840;         // 64 MB
constexpr size_t OFF_AGG   = 68296704;        // 64 MB   (total ~129.2 MB)

// acc (double) indices
constexpr int AC_BATCH = 0;    // 8*{sum,sumsq}
constexpr int AC_G     = 16;   // per b: G1[3], G2[6]
constexpr int AC_E     = 88;   // per (b,v): E1, Ea[3]
constexpr int AC_S2A   = 216;  // 64 col sums of agg
constexpr int AC_M2    = 280;  // 64*64 agg'agg

// ---------------- helpers ----------------
// fast erf via Abramowitz & Stegun 7.1.26 (max abs err 1.5e-7; output threshold is 8.25e-2)
__device__ __forceinline__ float erf_fast(float x) {
    float ax = fabsf(x);
    float t = 1.0f / (1.0f + 0.3275911f * ax);
    float y = t * (0.254829592f + t * (-0.284496736f + t * (1.421413741f +
              t * (-1.453152027f + t * 1.061405429f))));
    float r = 1.0f - y * __expf(-ax * ax);
    return copysignf(r, x);
}

__device__ __forceinline__ float gelu_f(float x) {
    return 0.5f * x * (1.0f + erf_fast(x * 0.7071067811865476f));
}

#define TF_ROUND(r) { x0 += x1; x1 = (x1 << (r)) | (x1 >> (32 - (r))); x1 ^= x0; }

__device__ __forceinline__ unsigned tf_random_bits(unsigned lo) {
    const unsigned ks0 = 0u, ks1 = 42u, ks2 = 0x1BD11BDAu ^ 0u ^ 42u;
#if TF_PARTITIONABLE
    unsigned x0 = 0u + ks0, x1 = lo + ks1;        // counter = (hi=0, lo=flat index)
#else
    unsigned j = lo & 0x01FFFFFFu;
    unsigned x0 = j + ks0, x1 = (j + 0x02000000u) + ks1;
#endif
    TF_ROUND(13) TF_ROUND(15) TF_ROUND(26) TF_ROUND(6)
    x0 += ks1; x1 += ks2 + 1u;
    TF_ROUND(17) TF_ROUND(29) TF_ROUND(16) TF_ROUND(24)
    x0 += ks2; x1 += ks0 + 2u;
    TF_ROUND(13) TF_ROUND(15) TF_ROUND(26) TF_ROUND(6)
    x0 += ks0; x1 += ks1 + 3u;
    TF_ROUND(17) TF_ROUND(29) TF_ROUND(16) TF_ROUND(24)
    x0 += ks1; x1 += ks2 + 4u;
    TF_ROUND(13) TF_ROUND(15) TF_ROUND(26) TF_ROUND(6)
    x0 += ks2; x1 += ks0 + 5u;
#if TF_PARTITIONABLE
    return x0 ^ x1;
#else
    return (lo < 0x02000000u) ? x0 : x1;
#endif
}

__device__ __forceinline__ float gumbel_from_bits(unsigned bits) {
    float fl = __uint_as_float((bits >> 9) | 0x3f800000u) - 1.0f;   // [0,1)
    float u  = fmaxf(1e-9f, fl + 1e-9f);                            // jax uniform(1e-9, 1.0)
    // inner log: keep accurate libm (v_log has poor relative accuracy for u->1, w = -log(u) ~ 1e-7)
    float w = -logf(u);
    // outer log: abs error of __logf on gumbel is ~|log w|*1e-6 — safe
    return -__logf(w);
}

__device__ __forceinline__ float wsum(float v) {
    for (int o = 32; o; o >>= 1) v += __shfl_down(v, o);
    return v;
}

// DPP-based full-wave (64 lane) max: ~12 VALU ops instead of 6 dependent DS shuffles.
// Valid because values are >= 0 (bound_ctrl=1 injects 0 as identity).
__device__ __forceinline__ float wave_max64_nonneg(float v) {
    int x;
    x = __builtin_amdgcn_update_dpp(0, __float_as_int(v), 0xB1, 0xf, 0xf, true);  // quad_perm [1,0,3,2]
    v = fmaxf(v, __int_as_float(x));
    x = __builtin_amdgcn_update_dpp(0, __float_as_int(v), 0x4E, 0xf, 0xf, true);  // quad_perm [2,3,0,1]
    v = fmaxf(v, __int_as_float(x));
    x = __builtin_amdgcn_update_dpp(0, __float_as_int(v), 0x141, 0xf, 0xf, true); // row_half_mirror
    v = fmaxf(v, __int_as_float(x));
    x = __builtin_amdgcn_update_dpp(0, __float_as_int(v), 0x140, 0xf, 0xf, true); // row_mirror
    v = fmaxf(v, __int_as_float(x));
    x = __builtin_amdgcn_update_dpp(0, __float_as_int(v), 0x142, 0xf, 0xf, true); // row_bcast:15
    v = fmaxf(v, __int_as_float(x));
    x = __builtin_amdgcn_update_dpp(0, __float_as_int(v), 0x143, 0xf, 0xf, true); // row_bcast:31
    v = fmaxf(v, __int_as_float(x));
    return __int_as_float(__builtin_amdgcn_readlane(__float_as_int(v), 63));      // wave-uniform
}

// ---------------- K1: farthest point sampling (latency-optimized v2) ----------------
// 256 threads / 4 waves, 16 points/thread in VGPRs. Per iteration critical path:
//   local min-update+argmax (VALU floor ~320cy) -> DPP wave max (~50cy) ->
//   ballot; the winning lane itself writes (val,idx) to parity LDS slot ->
//   ONE barrier -> all threads select block winner from 4 candidates ->
//   one ds_read_b128 for winner coords from float4 LDS mirror.
__global__ __launch_bounds__(256) void k_fps(const float* __restrict__ xyz,
                                             int* __restrict__ new_idx,
                                             float* __restrict__ new_xyz) {
    __shared__ __align__(16) float4 sxyz[4096];
    __shared__ __align__(16) float swv[2][4];
    __shared__ __align__(16) int   swi[2][4];
    int b = blockIdx.x, t = threadIdx.x, lane = t & 63, wid = t >> 6;
    const float* xb = xyz + (size_t)b * 12288;
    float px[16], py[16], pz[16], md[16];
    int i0 = t * 16;
#pragma unroll
    for (int j = 0; j < 16; j++) {
        int i = i0 + j;
        float x = xb[i * 3], y = xb[i * 3 + 1], z = xb[i * 3 + 2];
        px[j] = x; py[j] = y; pz[j] = z;
        sxyz[i] = make_float4(x, y, z, 0.0f);
        md[j] = __builtin_inff();
    }
    __syncthreads();
    float4 c0 = sxyz[0];
    float cx = c0.x, cy = c0.y, cz = c0.z;
    if (t == 0) {
        new_idx[b * 1024] = 0;
        new_xyz[(size_t)b * 3072 + 0] = cx;
        new_xyz[(size_t)b * 3072 + 1] = cy;
        new_xyz[(size_t)b * 3072 + 2] = cz;
    }
    int p = 0;
    for (int it = 1; it < 1024; ++it) {
        float bv = -1.0f; int bj = 0;
#pragma unroll
        for (int j = 0; j < 16; j++) {
            float dx = __fsub_rn(px[j], cx), dy = __fsub_rn(py[j], cy), dz = __fsub_rn(pz[j], cz);
            float d = __fadd_rn(__fadd_rn(__fmul_rn(dx, dx), __fmul_rn(dy, dy)), __fmul_rn(dz, dz));
            float m2 = fminf(md[j], d); md[j] = m2;
            if (m2 > bv) { bv = m2; bj = j; }
        }
        float mx = wave_max64_nonneg(bv);
        unsigned long long msk = __ballot(bv == mx);
        int winlane = __ffsll(msk) - 1;
        if (lane == winlane) { swv[p][wid] = bv; swi[p][wid] = i0 + bj; }
        __syncthreads();
        float4 vv = *(const float4*)&swv[p][0];
        int4   ii4 = *(const int4*)&swi[p][0];
        float best = vv.x; int ii = ii4.x;
        if (vv.y > best) { best = vv.y; ii = ii4.y; }
        if (vv.z > best) { best = vv.z; ii = ii4.z; }
        if (vv.w > best) { best = vv.w; ii = ii4.w; }
        float4 cw = sxyz[ii];
        cx = cw.x; cy = cw.y; cz = cw.z;
        if (t == 0) {
            new_idx[b * 1024 + it] = ii;
            size_t o3 = ((size_t)b * 1024 + it) * 3;
            new_xyz[o3] = cx; new_xyz[o3 + 1] = cy; new_xyz[o3 + 2] = cz;
        }
        p ^= 1;
    }
}

// ---------------- K2: ball query (first 32 by index within radius) ----------------
__global__ __launch_bounds__(256) void k_ball(const float* __restrict__ xyz,
                                              const float* __restrict__ new_xyz,
                                              int* __restrict__ gidx) {
    int gw = blockIdx.x * 4 + (threadIdx.x >> 6);
    int lane = threadIdx.x & 63;
    int b = gw >> 10;
    const float* xb = xyz + (size_t)b * 12288;
    float qx = new_xyz[gw * 3], qy = new_xyz[gw * 3 + 1], qz = new_xyz[gw * 3 + 2];
    int* out = gidx + (size_t)gw * 32;
    int have = 0;
    for (int c0 = 0; c0 < 4096; c0 += 64) {
        int i = c0 + lane;
        float dx = __fsub_rn(qx, xb[i * 3]);
        float dy = __fsub_rn(qy, xb[i * 3 + 1]);
        float dz = __fsub_rn(qz, xb[i * 3 + 2]);
        float d2 = __fadd_rn(__fadd_rn(__fmul_rn(dx, dx), __fmul_rn(dy, dy)), __fmul_rn(dz, dz));
        bool within = d2 < 0.04f;
        unsigned long long mv = __ballot(within);
        int rank = __popcll(mv & ((1ull << lane) - 1ull));
        int pos = have + rank;
        if (within && pos < 32) out[pos] = i;
        have += (int)__popcll(mv);
        if (have >= 32) break;
    }
    for (int j = have + lane; j < 32; j += 64) out[j] = -1;
}

// ---------------- K3: gather pass -> gf std moments + rel group moments ----------------
__global__ __launch_bounds__(256) void k_stats(const float* __restrict__ xyz,
                                               const float* __restrict__ f,
                                               const int* __restrict__ cidx,
                                               const int* __restrict__ new_idx,
                                               const int* __restrict__ gidx,
                                               const float* __restrict__ new_xyz,
                                               double* __restrict__ acc) {
    int b = blockIdx.x >> 5, blk = blockIdx.x & 31;
    int t = threadIdx.x, lane = t & 63;
    const float* xb = xyz + (size_t)b * 12288;
    const float* fb = f + ((size_t)b << 18);
    float mc[4][3];
#pragma unroll
    for (int v = 0; v < 4; v++) {
        int ci = cidx[v];
        mc[v][0] = xb[ci * 3]; mc[v][1] = xb[ci * 3 + 1]; mc[v][2] = xb[ci * 3 + 2];
    }
    float sum = 0.f, ssq = 0.f;
    float G1x = 0, G1y = 0, G1z = 0, Gxx = 0, Gxy = 0, Gxz = 0, Gyy = 0, Gyz = 0, Gzz = 0;
    float E1[4] = {0, 0, 0, 0}, Eax[4] = {0, 0, 0, 0}, Eay[4] = {0, 0, 0, 0}, Eaz[4] = {0, 0, 0, 0};
    for (int rr = 0; rr < 4; ++rr) {
        int row = blk * 1024 + rr * 256 + t;
        int s = row >> 5;
        int gi = gidx[((size_t)b << 15) + row];
        bool msk = gi < 0;
        int sg = (b << 10) + s;
        float nx = new_xyz[sg * 3], ny = new_xyz[sg * 3 + 1], nz = new_xyz[sg * 3 + 2];
        int nid = new_idx[sg];
        float gx = 0, gy = 0, gz = 0;
        if (!msk) { gx = xb[gi * 3]; gy = xb[gi * 3 + 1]; gz = xb[gi * 3 + 2]; }
        float a3 = __fsub_rn(gx, nx), a4 = __fsub_rn(gy, ny), a5 = __fsub_rn(gz, nz);
        sum += gx + gy + gz + a3 + a4 + a5;
        ssq += gx * gx + gy * gy + gz * gz + a3 * a3 + a4 * a4 + a5 * a5;
        const float4* fsp = (const float4*)(fb + ((size_t)nid << 6));
        int gi0 = msk ? 0 : gi;
        const float4* fip = (const float4*)(fb + ((size_t)gi0 << 6));
#pragma unroll
        for (int c4 = 0; c4 < 16; c4++) {
            float4 fs4 = fsp[c4];
            float4 fi4 = fip[c4];
            if (msk) { fi4.x = 0; fi4.y = 0; fi4.z = 0; fi4.w = 0; }
            float d0 = __fsub_rn(fi4.x, fs4.x), d1 = __fsub_rn(fi4.y, fs4.y);
            float d2 = __fsub_rn(fi4.z, fs4.z), d3 = __fsub_rn(fi4.w, fs4.w);
            sum += d0 + d1 + d2 + d3;
            ssq += d0 * d0 + d1 * d1 + d2 * d2 + d3 * d3;
        }
        G1x += gx; G1y += gy; G1z += gz;
        Gxx += gx * gx; Gxy += gx * gy; Gxz += gx * gz;
        Gyy += gy * gy; Gyz += gy * gz; Gzz += gz * gz;
#pragma unroll
        for (int v = 0; v < 4; v++) {
            float ax = __fsub_rn(gx, mc[v][0]), ay = __fsub_rn(gy, mc[v][1]), az = __fsub_rn(gz, mc[v][2]);
            float e = __fsqrt_rn(ax * ax + ay * ay + az * az);
            E1[v] += e; Eax[v] += e * gx; Eay[v] += e * gy; Eaz[v] += e * gz;
        }
    }
    sum = wsum(sum); ssq = wsum(ssq);
    G1x = wsum(G1x); G1y = wsum(G1y); G1z = wsum(G1z);
    Gxx = wsum(Gxx); Gxy = wsum(Gxy); Gxz = wsum(Gxz);
    Gyy = wsum(Gyy); Gyz = wsum(Gyz); Gzz = wsum(Gzz);
#pragma unroll
    for (int v = 0; v < 4; v++) {
        E1[v] = wsum(E1[v]); Eax[v] = wsum(Eax[v]); Eay[v] = wsum(Eay[v]); Eaz[v] = wsum(Eaz[v]);
    }
    if (lane == 0) {
        atomicAdd(&acc[AC_BATCH + b * 2 + 0], (double)sum);
        atomicAdd(&acc[AC_BATCH + b * 2 + 1], (double)ssq);
        double* Gb = acc + AC_G + b * 9;
        atomicAdd(&Gb[0], (double)G1x); atomicAdd(&Gb[1], (double)G1y); atomicAdd(&Gb[2], (double)G1z);
        atomicAdd(&Gb[3], (double)Gxx); atomicAdd(&Gb[4], (double)Gxy); atomicAdd(&Gb[5], (double)Gxz);
        atomicAdd(&Gb[6], (double)Gyy); atomicAdd(&Gb[7], (double)Gyz); atomicAdd(&Gb[8], (double)Gzz);
#pragma unroll
        for (int v = 0; v < 4; v++) {
            double* Eb = acc + AC_E + (b * 4 + v) * 4;
            atomicAdd(&Eb[0], (double)E1[v]);
            atomicAdd(&Eb[1], (double)Eax[v]);
            atomicAdd(&Eb[2], (double)Eay[v]);
            atomicAdd(&Eb[3], (double)Eaz[v]);
        }
    }
}

// ---------------- K4: prep (std scale, BN1 fold, mix_w transpose) ----------------
struct GS { double G1[3]; double G2[6]; double E1; double Ea[3]; double m[3]; };

__device__ __forceinline__ int g2i(int x, int y) {
    if (x > y) { int tt = x; x = y; y = tt; }
    return (x == 0) ? y : ((x == 1) ? (2 + y) : 5);
}

__device__ double pairsum(const GS& g, int ki, int ai, int kj, int aj) {
    const double R = 32768.0;
    if (ki > kj) { int tk = ki; ki = kj; kj = tk; int ta = ai; ai = aj; aj = ta; }
    switch (ki * 4 + kj) {
        case 0:  return g.G2[g2i(ai, aj)] - g.m[ai] * g.G1[aj] - g.m[aj] * g.G1[ai] + R * g.m[ai] * g.m[aj];
        case 1:  return g.Ea[ai] - g.m[ai] * g.E1;
        case 2:  return g.G2[g2i(ai, aj)] - g.m[ai] * g.G1[aj];
        case 3:  return (g.G1[ai] - R * g.m[ai]) * g.m[aj];
        case 5:  { double s = 0; for (int x = 0; x < 3; x++) s += g.G2[g2i(x, x)] - 2.0 * g.m[x] * g.G1[x] + R * g.m[x] * g.m[x]; return s; }
        case 6:  return g.Ea[aj];
        case 7:  return g.E1 * g.m[aj];
        case 10: return g.G2[g2i(ai, aj)];
        case 11: return g.G1[ai] * g.m[aj];
        case 15: return R * g.m[ai] * g.m[aj];
    }
    return 0.0;
}

__device__ __forceinline__ void chdec(int ch, int& kind, int& ax, double& sgn) {
    if (ch < 3)      { kind = 0; ax = ch;      sgn = -1.0; }
    else if (ch < 6) { kind = 0; ax = ch - 3;  sgn = 1.0; }
    else if (ch == 6){ kind = 1; ax = 0;       sgn = 1.0; }
    else if (ch < 10){ kind = 2; ax = ch - 7;  sgn = 1.0; }
    else             { kind = 3; ax = ch - 10; sgn = 1.0; }
}

__device__ GS load_gs(const double* acc, const float* xyz, const int* cidx, int grp) {
    GS g; int b = grp >> 2, v = grp & 3;
    const double* Gb = acc + AC_G + b * 9;
    g.G1[0] = Gb[0]; g.G1[1] = Gb[1]; g.G1[2] = Gb[2];
    for (int q = 0; q < 6; q++) g.G2[q] = Gb[3 + q];
    const double* Eb = acc + AC_E + grp * 4;
    g.E1 = Eb[0]; g.Ea[0] = Eb[1]; g.Ea[1] = Eb[2]; g.Ea[2] = Eb[3];
    int ci = cidx[v];
    g.m[0] = (double)xyz[(size_t)b * 12288 + ci * 3];
    g.m[1] = (double)xyz[(size_t)b * 12288 + ci * 3 + 1];
    g.m[2] = (double)xyz[(size_t)b * 12288 + ci * 3 + 2];
    return g;
}

__global__ __launch_bounds__(256) void k_prep(const double* __restrict__ acc,
                                              const float* __restrict__ xyz,
                                              const int* __restrict__ cidx,
                                              const float* __restrict__ m1w1,
                                              const float* __restrict__ m1b1,
                                              const float* __restrict__ m1g1,
                                              const float* __restrict__ m1be1,
                                              const float* __restrict__ mixw,
                                              float* __restrict__ scale,
                                              float* __restrict__ w1p,
                                              float* __restrict__ b1p,
                                              float* __restrict__ mixwt) {
    __shared__ double Sec[169];
    __shared__ double S1[13];
    int t = threadIdx.x;
    if (t < 8) {
        double sm = acc[AC_BATCH + t * 2], sq = acc[AC_BATCH + t * 2 + 1];
        double M = 2293760.0;
        double var = (sq - sm * sm / M) / (M - 1.0);
        float stdv = (float)sqrt(var);
        scale[t] = 1.0f / (stdv + 1e-5f);
    }
    for (int idx = t; idx < 8576; idx += 256) {
        int k = idx >> 6, o = idx & 63;
        mixwt[idx] = mixw[o * 134 + k];
    }
    if (t < 169) {
        int i = t / 13, j = t % 13;
        int ki, ai, kj, aj; double si, sj;
        chdec(i, ki, ai, si); chdec(j, kj, aj, sj);
        double val = 0;
        for (int grp = 0; grp < 32; grp++) {
            GS g = load_gs(acc, xyz, cidx, grp);
            val += si * sj * pairsum(g, ki, ai, kj, aj);
        }
        Sec[t] = val;
    } else if (t < 182) {
        int i = t - 169;
        int ki, ai; double si;
        chdec(i, ki, ai, si);
        double val = 0;
        const double R = 32768.0;
        for (int grp = 0; grp < 32; grp++) {
            GS g = load_gs(acc, xyz, cidx, grp);
            double tv;
            switch (ki) {
                case 0:  tv = si * (g.G1[ai] - R * g.m[ai]); break;
                case 1:  tv = g.E1; break;
                case 2:  tv = g.G1[ai]; break;
                default: tv = R * g.m[ai]; break;
            }
            val += tv;
        }
        S1[i] = val;
    }
    __syncthreads();
    if (t < 64) {
        double w[13];
        for (int k = 0; k < 13; k++) w[k] = (double)m1w1[t * 13 + k];
        double s1w = 0;
        for (int k = 0; k < 13; k++) s1w += w[k] * S1[k];
        double quad = 0;
        for (int i = 0; i < 13; i++) {
            double s = 0;
            for (int j = 0; j < 13; j++) s += Sec[i * 13 + j] * w[j];
            quad += w[i] * s;
        }
        double M1d = 1048576.0;
        double b1o = (double)m1b1[t];
        double mu = s1w / M1d + b1o;
        double E2 = (quad + 2.0 * b1o * s1w) / M1d + b1o * b1o;
        double var = E2 - mu * mu;
        double gg = (double)m1g1[t] / sqrt(var + 1e-5);
        for (int k = 0; k < 13; k++) w1p[t * 13 + k] = (float)(w[k] * gg);
        b1p[t] = (float)((b1o - mu) * gg + (double)m1be1[t]);
    }
}

// ---------------- K5: grouped_f = affine(gf)/std .. concat sampled -> mix GEMM ----------------
__global__ __launch_bounds__(256) void k_groupedf(const float* __restrict__ xyz,
                                                  const float* __restrict__ f,
                                                  const int* __restrict__ new_idx,
                                                  const int* __restrict__ gidx,
                                                  const float* __restrict__ new_xyz,
                                                  const float* __restrict__ scale_p,
                                                  const float* __restrict__ aw,
                                                  const float* __restrict__ ab,
                                                  const float* __restrict__ mixwt,
                                                  const float* __restrict__ mixb,
                                                  float* __restrict__ gf) {
    int r = blockIdx.x * 256 + threadIdx.x;
    int b = r >> 15;
    int rb = r & 32767;
    int s = rb >> 5;
    int gi = gidx[r];
    bool msk = gi < 0;
    int gi0 = msk ? 0 : gi;
    int sg = (b << 10) + s;
    int nid = new_idx[sg];
    float scale = scale_p[b];
    float nx = new_xyz[sg * 3], ny = new_xyz[sg * 3 + 1], nz = new_xyz[sg * 3 + 2];
    const float* xb = xyz + (size_t)b * 12288;
    const float* fb = f + ((size_t)b << 18);
    float gx = 0, gy = 0, gz = 0;
    if (!msk) { gx = xb[gi * 3]; gy = xb[gi * 3 + 1]; gz = xb[gi * 3 + 2]; }
    float acc[64];
#pragma unroll
    for (int o = 0; o < 64; o++) acc[o] = mixb[o];
    float va[6];
    va[0] = gx; va[1] = gy; va[2] = gz;
    va[3] = __fsub_rn(gx, nx); va[4] = __fsub_rn(gy, ny); va[5] = __fsub_rn(gz, nz);
#pragma unroll
    for (int k = 0; k < 6; k++) {
        float g = aw[k] * (va[k] * scale) + ab[k];
        const float* wt = mixwt + k * 64;
#pragma unroll
        for (int o = 0; o < 64; o++) acc[o] += g * wt[o];
    }
    const float4* fip = (const float4*)(fb + ((size_t)gi0 << 6));
    const float4* fsp = (const float4*)(fb + ((size_t)nid << 6));
    for (int c4 = 0; c4 < 16; c4++) {
        float4 fi = fip[c4];
        if (msk) { fi.x = 0; fi.y = 0; fi.z = 0; fi.w = 0; }
        float4 fs4 = fsp[c4];
        float dv[4] = {__fsub_rn(fi.x, fs4.x), __fsub_rn(fi.y, fs4.y),
                       __fsub_rn(fi.z, fs4.z), __fsub_rn(fi.w, fs4.w)};
#pragma unroll
        for (int u = 0; u < 4; u++) {
            int k = 6 + c4 * 4 + u;
            float g = aw[k] * (dv[u] * scale) + ab[k];
            const float* wt = mixwt + k * 64;
#pragma unroll
            for (int o = 0; o < 64; o++) acc[o] += g * wt[o];
        }
    }
    for (int c4 = 0; c4 < 16; c4++) {
        float4 fs4 = fsp[c4];
        float sv[4] = {fs4.x, fs4.y, fs4.z, fs4.w};
#pragma unroll
        for (int u = 0; u < 4; u++) {
            int k = 70 + c4 * 4 + u;
            const float* wt = mixwt + k * 64;
#pragma unroll
            for (int o = 0; o < 64; o++) acc[o] += sv[u] * wt[o];
        }
    }
    float4* dst = (float4*)(gf + ((size_t)r << 6));
#pragma unroll
    for (int c4 = 0; c4 < 16; c4++)
        dst[c4] = make_float4(acc[c4 * 4], acc[c4 * 4 + 1], acc[c4 * 4 + 2], acc[c4 * 4 + 3]);
}

// ---------------- K6: fused m1 -> gelu -> m1_w2 -> logits -> gumbel softmax -> agg ----------------
// sh[] is wave-private (indexed by wv): no __syncthreads needed in the rr loop —
// same-wave LDS RAW is ordered by lgkmcnt waits the compiler inserts.
__global__ __launch_bounds__(256) void k_fused(const float* __restrict__ xyz,
                                               const int* __restrict__ cidx,
                                               const int* __restrict__ gidx,
                                               const float* __restrict__ gf,
                                               const float* __restrict__ w1p,
                                               const float* __restrict__ b1p,
                                               const float* __restrict__ w2,
                                               const float* __restrict__ b2,
                                               float* __restrict__ agg) {
    __shared__ float sh[4][4][64];
    __shared__ float smc[4][3];
    int t = threadIdx.x, wv = t >> 6, lane = t & 63;
    int row0 = blockIdx.x * 64;
    int b = row0 >> 15;
    if (t < 12) {
        int v = t / 3, j = t % 3;
        smc[v][j] = xyz[(size_t)b * 12288 + cidx[v] * 3 + j];
    }
    float w1l[13];
#pragma unroll
    for (int k = 0; k < 13; k++) w1l[k] = w1p[lane * 13 + k];
    float b1l = b1p[lane], b2l = b2[lane];
    float w2r[64];
#pragma unroll
    for (int c4 = 0; c4 < 16; c4++) {
        float4 tmp = *(const float4*)(w2 + lane * 64 + c4 * 4);
        w2r[c4 * 4] = tmp.x; w2r[c4 * 4 + 1] = tmp.y; w2r[c4 * 4 + 2] = tmp.z; w2r[c4 * 4 + 3] = tmp.w;
    }
    __syncthreads();   // smc is cross-wave: keep this one
    float mcl[4][3];
#pragma unroll
    for (int v = 0; v < 4; v++) { mcl[v][0] = smc[v][0]; mcl[v][1] = smc[v][1]; mcl[v][2] = smc[v][2]; }
    int r = row0 + wv * 16;
    for (int rr = 0; rr < 16; ++rr, ++r) {
        int gi = gidx[r];
        bool msk = gi < 0;
        float gx = 0, gy = 0, gz = 0;
        if (!msk) {
            const float* p = xyz + (size_t)b * 12288 + (size_t)gi * 3;
            gx = p[0]; gy = p[1]; gz = p[2];
        }
        float gfo = gf[((size_t)r << 6) + lane];
#pragma unroll
        for (int v = 0; v < 4; v++) {
            float ax = __fsub_rn(gx, mcl[v][0]);
            float ay = __fsub_rn(gy, mcl[v][1]);
            float az = __fsub_rn(gz, mcl[v][2]);
            float eu = __fsqrt_rn(__fadd_rn(__fadd_rn(__fmul_rn(ax, ax), __fmul_rn(ay, ay)), __fmul_rn(az, az)));
            float h = b1l
                - ax * w1l[0] - ay * w1l[1] - az * w1l[2]
                + ax * w1l[3] + ay * w1l[4] + az * w1l[5]
                + eu * w1l[6] + gx * w1l[7] + gy * w1l[8] + gz * w1l[9]
                + mcl[v][0] * w1l[10] + mcl[v][1] * w1l[11] + mcl[v][2] * w1l[12];
            sh[wv][v][lane] = gelu_f(h);
        }
        float lg[4];
#pragma unroll
        for (int v = 0; v < 4; v++) {
            float a = b2l;
            const float4* hp = (const float4*)sh[wv][v];
#pragma unroll
            for (int c4 = 0; c4 < 16; c4++) {
                float4 hh = hp[c4];
                a += hh.x * w2r[c4 * 4] + hh.y * w2r[c4 * 4 + 1] + hh.z * w2r[c4 * 4 + 2] + hh.w * w2r[c4 * 4 + 3];
            }
            lg[v] = gfo * a;
        }
        unsigned base = ((unsigned)r << 8) + (unsigned)lane;
        float z0 = lg[0] + gumbel_from_bits(tf_random_bits(base));
        float z1 = lg[1] + gumbel_from_bits(tf_random_bits(base + 64u));
        float z2 = lg[2] + gumbel_from_bits(tf_random_bits(base + 128u));
        float z3 = lg[3] + gumbel_from_bits(tf_random_bits(base + 192u));
        float mx = fmaxf(fmaxf(z0, z1), fmaxf(z2, z3));
        float e0 = __expf(z0 - mx), e1 = __expf(z1 - mx), e2 = __expf(z2 - mx), e3 = __expf(z3 - mx);
        float inv = 1.0f / (e0 + e1 + e2 + e3);
        float av = (e0 * lg[0] + e1 * lg[1] + e2 * lg[2] + e3 * lg[3]) * inv + gfo;
        agg[((size_t)r << 6) + lane] = msk ? 0.0f : av;
    }
}

// ---------------- K7: syrk — M2 = agg' * agg, col sums ----------------
__global__ __launch_bounds__(256) void k_syrk(const float* __restrict__ agg,
                                              double* __restrict__ acc) {
    __shared__ float As[128][64];
    int t = threadIdx.x;
    int ti = t >> 4, tj = t & 15;
    float C[4][4] = {};
    float cs = 0.f;
    size_t base = (size_t)blockIdx.x * 1024 * 64;
    for (int tile = 0; tile < 8; ++tile) {
        const float4* src = (const float4*)(agg + base + (size_t)tile * 128 * 64);
#pragma unroll
        for (int i = 0; i < 8; i++) {
            int idx = t + i * 256;
            ((float4*)As)[idx] = src[idx];
        }
        __syncthreads();
        for (int rr = 0; rr < 128; ++rr) {
            float4 a = *(const float4*)&As[rr][ti * 4];
            float4 bb = *(const float4*)&As[rr][tj * 4];
            C[0][0] += a.x * bb.x; C[0][1] += a.x * bb.y; C[0][2] += a.x * bb.z; C[0][3] += a.x * bb.w;
            C[1][0] += a.y * bb.x; C[1][1] += a.y * bb.y; C[1][2] += a.y * bb.z; C[1][3] += a.y * bb.w;
            C[2][0] += a.z * bb.x; C[2][1] += a.z * bb.y; C[2][2] += a.z * bb.z; C[2][3] += a.z * bb.w;
            C[3][0] += a.w * bb.x; C[3][1] += a.w * bb.y; C[3][2] += a.w * bb.z; C[3][3] += a.w * bb.w;
            if (t < 64) cs += As[rr][t];
        }
        __syncthreads();
    }
    double* M2 = acc + AC_M2;
#pragma unroll
    for (int i = 0; i < 4; i++)
#pragma unroll
        for (int j = 0; j < 4; j++)
            atomicAdd(&M2[(ti * 4 + i) * 64 + (tj * 4 + j)], (double)C[i][j]);
    if (t < 64) atomicAdd(&acc[AC_S2A + t], (double)cs);
}

// ---------------- K7b: BN2 stats -> fold into W_comb / b_comb ----------------
__global__ __launch_bounds__(256) void k_comb(const double* __restrict__ acc,
                                              const float* __restrict__ m2w1,
                                              const float* __restrict__ m2b1,
                                              const float* __restrict__ m2g1,
                                              const float* __restrict__ m2be1,
                                              const float* __restrict__ m2w2,
                                              const float* __restrict__ m2b2,
                                              float* __restrict__ wcomb,
                                              float* __restrict__ bcomb) {
    __shared__ float W1s[128 * 64];
    __shared__ float g2s[128], ofss[128];
    int t = threadIdx.x;
    const double* S2a = acc + AC_S2A;
    const double* M2 = acc + AC_M2;
    if (t < 128) {
        float wf[64];
        for (int c = 0; c < 64; c++) wf[c] = m2w1[t * 64 + c];
        double sw = 0;
        for (int c = 0; c < 64; c++) sw += (double)wf[c] * S2a[c];
        double quad = 0;
        for (int i = 0; i < 64; i++) {
            double s = 0;
            for (int j = 0; j < 64; j++) s += (double)wf[j] * M2[i * 64 + j];
            quad += (double)wf[i] * s;
        }
        double Rd = 262144.0;
        double b1o = (double)m2b1[t];
        double mu = sw / Rd + b1o;
        double E2 = (quad + 2.0 * b1o * sw) / Rd + b1o * b1o;
        double var = E2 - mu * mu;
        double gg = (double)m2g1[t] / sqrt(var + 1e-5);
        g2s[t] = (float)gg;
        ofss[t] = (float)(((double)m2b1[t] - mu) * gg + (double)m2be1[t]);
    }
    __syncthreads();
    for (int idx = t; idx < 128 * 64; idx += 256) {
        int c = idx >> 6, k = idx & 63;
        W1s[idx] = g2s[c] * m2w1[c * 64 + k];
    }
    __syncthreads();
    for (int idx = t; idx < 128 * 64; idx += 256) {
        int o = idx >> 6, k = idx & 63;
        float s = 0;
        for (int c = 0; c < 128; c++) s += m2w2[o * 128 + c] * W1s[c * 64 + k];
        wcomb[idx] = s;
    }
    if (t < 128) {
        float s = m2b2[t];
        for (int c = 0; c < 128; c++) s += m2w2[t * 128 + c] * ofss[c];
        bcomb[t] = s;
    }
}

// ---------------- K8: final — composed m2 + res, gelu, max over NS ----------------
__global__ __launch_bounds__(256) void k_final(const float* __restrict__ agg,
                                               const float* __restrict__ gf,
                                               const float* __restrict__ wcomb,
                                               const float* __restrict__ bcomb,
                                               const float* __restrict__ resw,
                                               const float* __restrict__ resb,
                                               float* __restrict__ out_f) {
    __shared__ float rbuf[8][128];
    int t = threadIdx.x, wv = t >> 6, lane = t & 63;
    int which = lane >> 5, n = lane & 31;
    int gw = blockIdx.x * 8 + wv * 2 + which;
    size_t r = (size_t)gw * 32 + n;
    float ar[64], sk[64];
    const float4* ap = (const float4*)(agg + (r << 6));
    const float4* sp = (const float4*)(gf + (r << 6));
#pragma unroll
    for (int c4 = 0; c4 < 16; c4++) {
        float4 x = ap[c4];
        ar[c4 * 4] = x.x; ar[c4 * 4 + 1] = x.y; ar[c4 * 4 + 2] = x.z; ar[c4 * 4 + 3] = x.w;
        float4 y = sp[c4];
        sk[c4 * 4] = y.x; sk[c4 * 4 + 1] = y.y; sk[c4 * 4 + 2] = y.z; sk[c4 * 4 + 3] = y.w;
    }
    for (int o = 0; o < 128; o++) {
        float a1 = bcomb[o], a2 = resb[o];
        const float* wc = wcomb + o * 64;
        const float* rw = resw + o * 64;
#pragma unroll
        for (int c = 0; c < 64; c++) { a1 += ar[c] * wc[c]; a2 += sk[c] * rw[c]; }
        float g = gelu_f(a1 + a2);
#pragma unroll
        for (int off = 16; off; off >>= 1) g = fmaxf(g, __shfl_xor(g, off));
        if (n == 0) rbuf[wv * 2 + which][o] = g;
    }
    __syncthreads();
    int base = blockIdx.x * 8;
    for (int i = t; i < 1024; i += 256) {
        int lr = i >> 7, o = i & 127;
        out_f[(size_t)(base + lr) * 128 + o] = rbuf[lr][o];
    }
}

// ---------------- launch ----------------
extern "C" void kernel_launch(void* const* d_in, const int* in_sizes, int n_in,
                              void* d_out, int out_size, void* d_ws, size_t ws_size,
                              hipStream_t stream) {
    (void)in_sizes; (void)n_in; (void)out_size; (void)ws_size;
    const float* xyz  = (const float*)d_in[0];
    const float* f    = (const float*)d_in[1];
    const int*   cidx = (const int*)d_in[2];
    const float* aw   = (const float*)d_in[3];
    const float* ab   = (const float*)d_in[4];
    const float* mixw = (const float*)d_in[5];
    const float* mixb = (const float*)d_in[6];
    const float* m1w1 = (const float*)d_in[7];
    const float* m1b1 = (const float*)d_in[8];
    const float* m1g1 = (const float*)d_in[9];
    const float* m1be1= (const float*)d_in[10];
    const float* m1w2 = (const float*)d_in[11];
    const float* m1b2 = (const float*)d_in[12];
    const float* m2w1 = (const float*)d_in[13];
    const float* m2b1 = (const float*)d_in[14];
    const float* m2g1 = (const float*)d_in[15];
    const float* m2be1= (const float*)d_in[16];
    const float* m2w2 = (const float*)d_in[17];
    const float* m2b2 = (const float*)d_in[18];
    const float* resw = (const float*)d_in[19];
    const float* resb = (const float*)d_in[20];

    float* out_f   = (float*)d_out;
    float* out_xyz = out_f + (size_t)B_ * S_ * COUT_;

    char* ws = (char*)d_ws;
    double* acc  = (double*)(ws + OFF_ACC);
    float* scale = (float*)(ws + OFF_SCALE);
    float* w1p   = (float*)(ws + OFF_W1P);
    float* b1p   = (float*)(ws + OFF_B1P);
    float* wcomb = (float*)(ws + OFF_WCOMB);
    float* bcomb = (float*)(ws + OFF_BCOMB);
    float* mixwt = (float*)(ws + OFF_MIXWT);
    int*   nidx  = (int*)(ws + OFF_NIDX);
    int*   gidx  = (int*)(ws + OFF_GIDX);
    float* gf    = (float*)(ws + OFF_GF);
    float* agg   = (float*)(ws + OFF_AGG);

    hipMemsetAsync(ws, 0, ACC_BYTES, stream);
    hipLaunchKernelGGL(k_fps,      dim3(8),    dim3(256),  0, stream, xyz, nidx, out_xyz);
    hipLaunchKernelGGL(k_ball,     dim3(2048), dim3(256),  0, stream, xyz, out_xyz, gidx);
    hipLaunchKernelGGL(k_stats,    dim3(256),  dim3(256),  0, stream, xyz, f, cidx, nidx, gidx, out_xyz, acc);
    hipLaunchKernelGGL(k_prep,     dim3(1),    dim3(256),  0, stream, acc, xyz, cidx, m1w1, m1b1, m1g1, m1be1, mixw, scale, w1p, b1p, mixwt);
    hipLaunchKernelGGL(k_groupedf, dim3(1024), dim3(256),  0, stream, xyz, f, nidx, gidx, out_xyz, scale, aw, ab, mixwt, mixb, gf);
    hipLaunchKernelGGL(k_fused,    dim3(4096), dim3(256),  0, stream, xyz, cidx, gidx, gf, w1p, b1p, m1w2, m1b2, agg);
    hipLaunchKernelGGL(k_syrk,     dim3(256),  dim3(256),  0, stream, agg, acc);
    hipLaunchKernelGGL(k_comb,     dim3(1),    dim3(256),  0, stream, acc, m2w1, m2b1, m2g1, m2be1, m2w2, m2b2, wcomb, bcomb);
    hipLaunchKernelGGL(k_final,    dim3(1024), dim3(256),  0, stream, agg, gf, wcomb, bcomb, resw, resb, out_f);
}